// Round 12
// baseline (1402.268 us; speedup 1.0000x reference)
//
#include <hip/hip_runtime.h>

#define K_NN 20
#define LN_EPS 1e-5f
#define NEG_SLOPE 0.2f
#define BUFSZ 12
#define ARRSZ 32
#define NSLICE 16

__device__ __forceinline__ unsigned ordf(float f){
  unsigned u = __float_as_uint(f);
  return u ^ (((unsigned)((int)u >> 31)) | 0x80000000u);
}
__device__ __forceinline__ float unordf(unsigned u){
  unsigned m = ((int)u < 0) ? 0x80000000u : 0xFFFFFFFFu;
  return __uint_as_float(u ^ m);
}

__device__ __forceinline__ void ce_desc(unsigned long long &a, unsigned long long &b){
  unsigned long long mx = a>b ? a : b;
  unsigned long long mn = a>b ? b : a;
  a = mx; b = mn;
}

__device__ __forceinline__ void sort16_desc(unsigned long long (&v)[16]){
  #pragma unroll
  for (int k=2;k<=16;k<<=1){
    #pragma unroll
    for (int j=k>>1;j>0;j>>=1){
      #pragma unroll
      for (int i=0;i<16;++i){
        int l = i ^ j;
        if (l > i){
          if ((i & k) == 0) ce_desc(v[i], v[l]);
          else              ce_desc(v[l], v[i]);
        }
      }
    }
  }
}

// full 32-wide bitonic merge cleanup (valid for any genuine 32-long bitonic
// sequence). Round-8 lesson: never prune with virtual pads.
__device__ __forceinline__ void bmerge32_desc(unsigned long long (&v)[32]){
  #pragma unroll
  for (int d=16; d>0; d>>=1){
    #pragma unroll
    for (int i=0;i<32;++i){
      if ((i & d) == 0) ce_desc(v[i], v[i|d]);
    }
  }
}

// ---------------- normalize (+ fused layer-1 xx) ----------------
__global__ __launch_bounds__(1024) void normalize_kernel(const float* __restrict__ x,
                                                         float* __restrict__ xn,
                                                         float* __restrict__ xxo, int N){
  __shared__ float red[1024];
  __shared__ float ms[4];
  const int b = blockIdx.x;
  const int t = threadIdx.x;
  const float* xb = x + (size_t)b*3*N;
  float s0=0.f,s1=0.f,s2=0.f;
  for (int n=t;n<N;n+=1024){ s0+=xb[n]; s1+=xb[N+n]; s2+=xb[2*N+n]; }
  red[t]=s0; __syncthreads();
  for(int o=512;o>0;o>>=1){ if(t<o) red[t]+=red[t+o]; __syncthreads(); }
  if(!t) ms[0]=red[0]/(float)N; __syncthreads();
  red[t]=s1; __syncthreads();
  for(int o=512;o>0;o>>=1){ if(t<o) red[t]+=red[t+o]; __syncthreads(); }
  if(!t) ms[1]=red[0]/(float)N; __syncthreads();
  red[t]=s2; __syncthreads();
  for(int o=512;o>0;o>>=1){ if(t<o) red[t]+=red[t+o]; __syncthreads(); }
  if(!t) ms[2]=red[0]/(float)N; __syncthreads();
  const float m0=ms[0], m1=ms[1], m2=ms[2];
  float mx=0.f;
  for (int n=t;n<N;n+=1024){
    float a=xb[n]-m0, c1=xb[N+n]-m1, c2=xb[2*N+n]-m2;
    mx = fmaxf(mx, a*a+c1*c1+c2*c2);
  }
  red[t]=mx; __syncthreads();
  for(int o=512;o>0;o>>=1){ if(t<o) red[t]=fmaxf(red[t],red[t+o]); __syncthreads(); }
  if(!t) ms[3]=sqrtf(red[0])+1e-8f; __syncthreads();
  const float md=ms[3];
  for (int n=t;n<N;n+=1024){
    float a=xb[n]-m0, c1=xb[N+n]-m1, c2=xb[2*N+n]-m2;
    float4 v; v.x=a/md; v.y=c1/md; v.z=c2/md; v.w=0.f;
    reinterpret_cast<float4*>(xn)[(size_t)b*N+n]=v;
    float s=0.f;
    s=fmaf(v.x,v.x,s); s=fmaf(v.y,v.y,s); s=fmaf(v.z,v.z,s); s=fmaf(v.w,v.w,s);
    xxo[b*N+n]=s;
  }
}

// ---------------- KNN: 512 queries/block x 256-candidate LDS-staged slice ----------------
// grid = (BN/512 query groups) x 16 slices. Candidates+xx staged once to LDS
// (coalesced), hot loop reads LDS broadcast only (no s_loads). Seed/flush
// logic identical to the proven round-9/10 core. Each thread owns one query
// and emits its sorted top-20 of this slice directly to global partial lists.
template<int CP4>
__global__ __launch_bounds__(512,4) void knn_kernel(const float* __restrict__ feat,
                                                    const float* __restrict__ xx,
                                                    unsigned* __restrict__ pd32,
                                                    unsigned char* __restrict__ pi8,
                                                    int N, int BN){
  constexpr int STAGEB = CP4*256*16;
  __shared__ char smem[STAGEB + 1024 + BUFSZ*512*4 + BUFSZ*512];
  float4* scoord = (float4*)smem;                                   // [256*CP4]
  float*  sxx    = (float*)(smem + STAGEB);                         // [256]
  float*  pdbuf  = (float*)(smem + STAGEB + 1024);                  // [BUFSZ*512]
  unsigned char* idxbuf = (unsigned char*)(smem + STAGEB + 1024 + BUFSZ*512*4);

  const int gpb = N >> 9;                    // 512-query groups per batch
  const int gq  = blockIdx.x >> 4;
  const int s   = blockIdx.x & (NSLICE-1);
  const int b   = gq / gpb;
  const int n0  = (gq - b*gpb) << 9;
  const int tid = threadIdx.x;
  const int bN  = b*N;
  const int m0  = s << 8;
  const float4* fb = reinterpret_cast<const float4*>(feat);

  // ---- stage slice candidates + xx (coalesced) ----
  {
    const float4* src = fb + (size_t)(bN + m0)*CP4;
    for (int j = tid; j < 256*CP4; j += 512) scoord[j] = src[j];
    if (tid < 256) sxx[tid] = xx[bN + m0 + tid];
  }
  float4 own[CP4];
  #pragma unroll
  for (int i=0;i<CP4;++i) own[i] = fb[(size_t)(bN + n0 + tid)*CP4 + i];
  __syncthreads();

  auto pdof = [&](int j)->float{             // j in [0,256): slice-local
    const float4* cp = scoord + j*CP4;       // LDS broadcast (wave-uniform addr)
    float d0=0.f, d1=0.f;
    #pragma unroll
    for (int i=0;i<CP4;++i){
      float4 c = cp[i];
      d0 = fmaf(own[i].x,c.x,d0);
      d1 = fmaf(own[i].y,c.y,d1);
      d0 = fmaf(own[i].z,c.z,d0);
      d1 = fmaf(own[i].w,c.w,d1);
    }
    return fmaf(2.f, d0+d1, -sxx[j]);
  };

  unsigned long long arr[ARRSZ];             // sorted descending at all times
  float thresh;
  int cnt = 0;

  // ---- seed: exact sorted top-32 of first 32 candidates (genuine valley-32) ----
  {
    unsigned long long bv1[16], bv2[16];
    #pragma unroll
    for (int j=0;j<16;++j){
      float pd = pdof(j);
      bv1[j] = ((unsigned long long)ordf(pd)<<32) | (unsigned)((m0+j) ^ 0xFFFF);
    }
    sort16_desc(bv1);
    #pragma unroll
    for (int j=0;j<16;++j){
      float pd = pdof(16+j);
      bv2[j] = ((unsigned long long)ordf(pd)<<32) | (unsigned)((m0+16+j) ^ 0xFFFF);
    }
    sort16_desc(bv2);
    #pragma unroll
    for (int i=0;i<ARRSZ;++i) arr[i] = (i<16) ? bv1[i] : bv2[31-i];
    bmerge32_desc(arr);
    thresh = unordf((unsigned)(arr[K_NN-1]>>32));
  }

  auto do_flush = [&](){
    unsigned long long bv[16];
    #pragma unroll
    for (int q=0;q<16;++q){
      unsigned long long key = 0ull;
      if (q<BUFSZ){
        float pd = pdbuf[q*512 + tid];
        unsigned j8 = idxbuf[q*512 + tid];
        key = ((unsigned long long)ordf(pd)<<32) | (unsigned)((m0+(int)j8) ^ 0xFFFF);
      }
      bv[q] = (q < cnt) ? key : 0ull;
    }
    sort16_desc(bv);
    #pragma unroll
    for (int i=16;i<32;++i){
      unsigned long long t2 = bv[31-i];
      arr[i] = arr[i] > t2 ? arr[i] : t2;
    }
    bmerge32_desc(arr);                      // valley-32 -> sorted desc (proven)
    thresh = unordf((unsigned)(arr[K_NN-1]>>32));
    cnt = 0;
  };

  // ---- main loop: chunks of 4 candidates, j = 32..255 ----
  constexpr int C = 4;
  for (int ch=0; ch<(256-32)/C; ++ch){
    const int jc = 32 + ch*C;
    float pdv[C];
    #pragma unroll
    for (int j=0;j<C;++j) pdv[j] = pdof(jc+j);
    #pragma unroll
    for (int j=0;j<C;++j){
      if (pdv[j] >= thresh){
        pdbuf[cnt*512 + tid]  = pdv[j];
        idxbuf[cnt*512 + tid] = (unsigned char)(jc+j);
        ++cnt;
      }
    }
    if (__ballot(cnt >= BUFSZ-C)) do_flush();   // pre-chunk cnt <= 7 -> max fill 11
  }
  if (__ballot(cnt > 0)) do_flush();

  // ---- emit this slice's sorted top-20 for this thread's query ----
  {
    const size_t p = (size_t)(bN + n0 + tid);
    unsigned*       od = pd32 + ((size_t)s*BN + p)*K_NN;
    unsigned char*  oi = pi8  + ((size_t)s*BN + p)*K_NN;
    #pragma unroll
    for (int k=0;k<K_NN;++k){
      od[k] = (unsigned)(arr[k]>>32);
      unsigned m = ((unsigned)arr[k] ^ 0xFFFFu) & 0xFFFFu;
      oi[k] = (unsigned char)(m & 255u);
    }
  }
}

// ---------------- fused: 16-way merge of slice lists + ctr half matmul ----------------
template<int CIN,int CP4,int O>
__global__ __launch_bounds__(256) void merge_ctr_kernel(const unsigned* __restrict__ pd32,
                                                        const unsigned char* __restrict__ pi8,
                                                        int* __restrict__ idx_out,
                                                        const float* __restrict__ feat,
                                                        const float* __restrict__ W,
                                                        float* __restrict__ h0, int total){
  int i = blockIdx.x*256 + threadIdx.x;
  if (i>=total) return;
  // ---- 16-way merge of sorted slice lists ----
  {
    auto keyat = [&](int s, int pos)->unsigned long long{
      unsigned d = pd32[((size_t)s*total + i)*K_NN + pos];
      unsigned j8 = pi8[((size_t)s*total + i)*K_NN + pos];
      unsigned m = (unsigned)(s*256) + j8;
      return ((unsigned long long)d<<16) | (unsigned)((m ^ 0xFFFF) & 0xFFFFu);
    };
    unsigned long long heads[NSLICE];
    #pragma unroll
    for (int j=0;j<NSLICE;++j) heads[j] = keyat(j, 0);
    unsigned long long pk0=0ull, pk1=0ull;   // 8x8-bit counters each
    int* op = idx_out + (size_t)i*K_NN;
    for (int k=0;k<K_NN;++k){
      unsigned long long best=heads[0]; int bj=0;
      #pragma unroll
      for (int j=1;j<NSLICE;++j){ bool gg=heads[j]>best; best=gg?heads[j]:best; bj=gg?j:bj; }
      op[k] = (int)(((unsigned)best & 0xFFFFu) ^ 0xFFFFu);
      unsigned pos;
      if (bj < 8){ pos = (unsigned)((pk0>>(bj*8))&0xFFull)+1u; pk0 += (1ull<<(bj*8)); }
      else       { pos = (unsigned)((pk1>>((bj-8)*8))&0xFFull)+1u; pk1 += (1ull<<((bj-8)*8)); }
      unsigned long long nv = 0ull;
      if (pos < K_NN) nv = keyat(bj, (int)pos);
      #pragma unroll
      for (int j=0;j<NSLICE;++j) heads[j]=(j==bj)?nv:heads[j];
    }
  }
  // ---- ctr half of the edge matmul ----
  {
    const float4* p = reinterpret_cast<const float4*>(feat)+(size_t)i*CP4;
    float c[CP4*4];
    #pragma unroll
    for (int j=0;j<CP4;++j){
      float4 v=p[j];
      c[4*j+0]=v.x; c[4*j+1]=v.y; c[4*j+2]=v.z; c[4*j+3]=v.w;
    }
    float* hp = h0 + (size_t)i*O;
    #pragma unroll
    for (int o=0;o<O;++o){
      const float* wr = W + o*(2*CIN) + CIN;   // uniform -> s_load
      float a=0.f;
      #pragma unroll
      for (int cc=0;cc<CIN;++cc) a=fmaf(wr[cc],c[cc],a);
      hp[o]=a;
    }
  }
}

// ---------------- edge conv: thread per (point, neighbor); fused next-layer xx ----------------
template<int CIN,int CP4,int O>
__global__ __launch_bounds__(320) void edge_kernel(const float* __restrict__ feat,
      const int* __restrict__ knn_idx, const float* __restrict__ h0,
      const float* __restrict__ W, const float* __restrict__ g, const float* __restrict__ bb,
      float* __restrict__ outf, float* __restrict__ xxo, int N){
  __shared__ unsigned ob[16*O];
  const int t = threadIdx.x;
  const int p = t/K_NN, k = t - p*K_NN;
  const int b = blockIdx.y;
  const int n = blockIdx.x*16 + p;
  const int bN = b*N;
  for (int v=t; v<16*O; v+=320) ob[v]=0u;
  __syncthreads();
  const int m = knn_idx[(size_t)(bN+n)*K_NN + k];
  const float4* fb = reinterpret_cast<const float4*>(feat);
  float d[CP4*4];
  #pragma unroll
  for (int j=0;j<CP4;++j){
    float4 a = fb[(size_t)(bN+m)*CP4+j];
    float4 c = fb[(size_t)(bN+n)*CP4+j];
    d[4*j+0]=a.x-c.x; d[4*j+1]=a.y-c.y; d[4*j+2]=a.z-c.z; d[4*j+3]=a.w-c.w;
  }
  float h[O];
  const float4* hp = reinterpret_cast<const float4*>(h0 + (size_t)(bN+n)*O);
  #pragma unroll
  for (int j=0;j<O/4;++j){ float4 v=hp[j]; h[4*j]=v.x; h[4*j+1]=v.y; h[4*j+2]=v.z; h[4*j+3]=v.w; }
  #pragma unroll
  for (int o=0;o<O;++o){
    const float* wr = W + o*(2*CIN);          // uniform -> s_load
    float a=h[o];
    #pragma unroll
    for (int cc=0;cc<CIN;++cc) a=fmaf(wr[cc],d[cc],a);
    h[o]=a;
  }
  float mean=0.f;
  #pragma unroll
  for (int o=0;o<O;++o) mean+=h[o];
  mean *= (1.f/(float)O);
  float var=0.f;
  #pragma unroll
  for (int o=0;o<O;++o){ float dd=h[o]-mean; var=fmaf(dd,dd,var); }
  var *= (1.f/(float)O);
  const float r = rsqrtf(var+LN_EPS);
  #pragma unroll
  for (int o=0;o<O;++o){
    float hv = (h[o]-mean)*r*g[o]+bb[o];
    hv = (hv>=0.f)? hv : NEG_SLOPE*hv;
    atomicMax(&ob[p*O+o], ordf(hv));
  }
  __syncthreads();
  for (int v=t; v<16*O; v+=320){
    int pp=v/O, oo=v-pp*O;
    outf[(size_t)(bN+blockIdx.x*16+pp)*O+oo]=unordf(ob[v]);
  }
  if (t < 16){
    float s=0.f;
    for (int oo=0;oo<O;++oo){
      float f = unordf(ob[t*O+oo]);
      s = fmaf(f,f,s);
    }
    xxo[bN + blockIdx.x*16 + t] = s;
  }
}

// ---------------- global max pool over points ----------------
__global__ __launch_bounds__(256) void final_max_kernel(const float* __restrict__ x1,
    const float* __restrict__ x2, const float* __restrict__ x3, const float* __restrict__ x4,
    float* __restrict__ out, int N){
  __shared__ float red[256];
  const int L=blockIdx.x, b=blockIdx.y;
  const float* f; int O, off;
  if (L==0){f=x1;O=16;off=0;}
  else if (L==1){f=x2;O=16;off=16;}
  else if (L==2){f=x3;O=32;off=32;}
  else {f=x4;O=64;off=64;}
  const int t=threadIdx.x;
  const int c=t%O, s=t/O, S=256/O;
  float acc=-3.402823466e38f;
  for (int n=s;n<N;n+=S) acc=fmaxf(acc, f[(size_t)(b*N+n)*O+c]);
  red[t]=acc; __syncthreads();
  if (t<O){
    float a=red[t];
    for (int ss=1;ss<S;++ss) a=fmaxf(a,red[ss*O+t]);
    out[b*128+off+t]=a;
  }
}

extern "C" void kernel_launch(void* const* d_in, const int* in_sizes, int n_in,
                              void* d_out, int out_size, void* d_ws, size_t ws_size,
                              hipStream_t stream){
  const float* x  = (const float*)d_in[0];
  const float* W1 = (const float*)d_in[1];  const float* g1=(const float*)d_in[2];  const float* b1=(const float*)d_in[3];
  const float* W2 = (const float*)d_in[4];  const float* g2=(const float*)d_in[5];  const float* b2=(const float*)d_in[6];
  const float* W3 = (const float*)d_in[7];  const float* g3=(const float*)d_in[8];  const float* b3=(const float*)d_in[9];
  const float* W4 = (const float*)d_in[10]; const float* g4=(const float*)d_in[11]; const float* b4=(const float*)d_in[12];
  float* out=(float*)d_out;
  const int B=4;
  const int N=in_sizes[0]/(3*B);
  const int BN=B*N;

  char* ws=(char*)d_ws;
  size_t off=0;
  auto alloc=[&](size_t bytes)->void*{ void* p=ws+off; off=(off+bytes+255)&~(size_t)255; return p; };
  float* xn =(float*)alloc((size_t)BN*4*4);
  float* x1 =(float*)alloc((size_t)BN*16*4);
  float* x2 =(float*)alloc((size_t)BN*16*4);
  float* x3 =(float*)alloc((size_t)BN*32*4);
  float* x4 =(float*)alloc((size_t)BN*64*4);
  float* xxb=(float*)alloc((size_t)BN*4);
  int*   knn=(int*)  alloc((size_t)BN*K_NN*4);
  float* h0 =(float*)alloc((size_t)BN*64*4);
  unsigned*      pd32=(unsigned*)     alloc((size_t)NSLICE*BN*K_NN*4);  // 21.0 MB
  unsigned char* pi8 =(unsigned char*)alloc((size_t)NSLICE*BN*K_NN);    //  5.2 MB

  dim3 pb((BN+255)/256), tb(256);
  dim3 kb((BN/512)*NSLICE), kt(512);
  dim3 eb(N/16,B), et(320);

  normalize_kernel<<<dim3(B),dim3(1024),0,stream>>>(x,xn,xxb,N);

  // layer 1: 3 -> 16
  knn_kernel<1><<<kb,kt,0,stream>>>(xn,xxb,pd32,pi8,N,BN);
  merge_ctr_kernel<3,1,16><<<pb,tb,0,stream>>>(pd32,pi8,knn,xn,W1,h0,BN);
  edge_kernel<3,1,16><<<eb,et,0,stream>>>(xn,knn,h0,W1,g1,b1,x1,xxb,N);

  // layer 2: 16 -> 16
  knn_kernel<4><<<kb,kt,0,stream>>>(x1,xxb,pd32,pi8,N,BN);
  merge_ctr_kernel<16,4,16><<<pb,tb,0,stream>>>(pd32,pi8,knn,x1,W2,h0,BN);
  edge_kernel<16,4,16><<<eb,et,0,stream>>>(x1,knn,h0,W2,g2,b2,x2,xxb,N);

  // layer 3: 16 -> 32
  knn_kernel<4><<<kb,kt,0,stream>>>(x2,xxb,pd32,pi8,N,BN);
  merge_ctr_kernel<16,4,32><<<pb,tb,0,stream>>>(pd32,pi8,knn,x2,W3,h0,BN);
  edge_kernel<16,4,32><<<eb,et,0,stream>>>(x2,knn,h0,W3,g3,b3,x3,xxb,N);

  // layer 4: 32 -> 64
  knn_kernel<8><<<kb,kt,0,stream>>>(x3,xxb,pd32,pi8,N,BN);
  merge_ctr_kernel<32,8,64><<<pb,tb,0,stream>>>(pd32,pi8,knn,x3,W4,h0,BN);
  edge_kernel<32,8,64><<<eb,et,0,stream>>>(x3,knn,h0,W4,g4,b4,x4,xxb,N);

  final_max_kernel<<<dim3(4,B),dim3(256),0,stream>>>(x1,x2,x3,x4,out,N);
}

// Round 13
// 1377.787 us; speedup vs baseline: 1.0178x; 1.0178x over previous
//
#include <hip/hip_runtime.h>

#define K_NN 20
#define LN_EPS 1e-5f
#define NEG_SLOPE 0.2f
#define BUFSZ 12
#define ARRSZ 32
#define NSLICE 16

__device__ __forceinline__ unsigned ordf(float f){
  unsigned u = __float_as_uint(f);
  return u ^ (((unsigned)((int)u >> 31)) | 0x80000000u);
}
__device__ __forceinline__ float unordf(unsigned u){
  unsigned m = ((int)u < 0) ? 0x80000000u : 0xFFFFFFFFu;
  return __uint_as_float(u ^ m);
}

__device__ __forceinline__ void ce_desc(unsigned long long &a, unsigned long long &b){
  unsigned long long mx = a>b ? a : b;
  unsigned long long mn = a>b ? b : a;
  a = mx; b = mn;
}

__device__ __forceinline__ void sort16_desc(unsigned long long (&v)[16]){
  #pragma unroll
  for (int k=2;k<=16;k<<=1){
    #pragma unroll
    for (int j=k>>1;j>0;j>>=1){
      #pragma unroll
      for (int i=0;i<16;++i){
        int l = i ^ j;
        if (l > i){
          if ((i & k) == 0) ce_desc(v[i], v[l]);
          else              ce_desc(v[l], v[i]);
        }
      }
    }
  }
}

// full 32-wide bitonic merge cleanup (valid for any genuine 32-long bitonic
// sequence). Round-8 lesson: never prune with virtual pads.
__device__ __forceinline__ void bmerge32_desc(unsigned long long (&v)[32]){
  #pragma unroll
  for (int d=16; d>0; d>>=1){
    #pragma unroll
    for (int i=0;i<32;++i){
      if ((i & d) == 0) ce_desc(v[i], v[i|d]);
    }
  }
}

// ---------------- normalize (+ fused layer-1 xx) ----------------
__global__ __launch_bounds__(1024) void normalize_kernel(const float* __restrict__ x,
                                                         float* __restrict__ xn,
                                                         float* __restrict__ xxo, int N){
  __shared__ float red[1024];
  __shared__ float ms[4];
  const int b = blockIdx.x;
  const int t = threadIdx.x;
  const float* xb = x + (size_t)b*3*N;
  float s0=0.f,s1=0.f,s2=0.f;
  for (int n=t;n<N;n+=1024){ s0+=xb[n]; s1+=xb[N+n]; s2+=xb[2*N+n]; }
  red[t]=s0; __syncthreads();
  for(int o=512;o>0;o>>=1){ if(t<o) red[t]+=red[t+o]; __syncthreads(); }
  if(!t) ms[0]=red[0]/(float)N; __syncthreads();
  red[t]=s1; __syncthreads();
  for(int o=512;o>0;o>>=1){ if(t<o) red[t]+=red[t+o]; __syncthreads(); }
  if(!t) ms[1]=red[0]/(float)N; __syncthreads();
  red[t]=s2; __syncthreads();
  for(int o=512;o>0;o>>=1){ if(t<o) red[t]+=red[t+o]; __syncthreads(); }
  if(!t) ms[2]=red[0]/(float)N; __syncthreads();
  const float m0=ms[0], m1=ms[1], m2=ms[2];
  float mx=0.f;
  for (int n=t;n<N;n+=1024){
    float a=xb[n]-m0, c1=xb[N+n]-m1, c2=xb[2*N+n]-m2;
    mx = fmaxf(mx, a*a+c1*c1+c2*c2);
  }
  red[t]=mx; __syncthreads();
  for(int o=512;o>0;o>>=1){ if(t<o) red[t]=fmaxf(red[t],red[t+o]); __syncthreads(); }
  if(!t) ms[3]=sqrtf(red[0])+1e-8f; __syncthreads();
  const float md=ms[3];
  for (int n=t;n<N;n+=1024){
    float a=xb[n]-m0, c1=xb[N+n]-m1, c2=xb[2*N+n]-m2;
    float4 v; v.x=a/md; v.y=c1/md; v.z=c2/md; v.w=0.f;
    reinterpret_cast<float4*>(xn)[(size_t)b*N+n]=v;
    float s=0.f;
    s=fmaf(v.x,v.x,s); s=fmaf(v.y,v.y,s); s=fmaf(v.z,v.z,s); s=fmaf(v.w,v.w,s);
    xxo[b*N+n]=s;
  }
}

// ---------------- KNN: 512 queries/block x 256-candidate LDS-staged slice ----------------
// Round-12 core (passed, absmax 0.0). ONLY change: partial-list emit is now
// TRANSPOSED ([s][k][q], lane-coalesced stores) — round 12's per-thread
// [q][k] layout caused full-line RMW HBM traffic (679 MB WRITE/dispatch).
template<int CP4>
__global__ __launch_bounds__(512,4) void knn_kernel(const float* __restrict__ feat,
                                                    const float* __restrict__ xx,
                                                    unsigned* __restrict__ pd32,
                                                    unsigned char* __restrict__ pi8,
                                                    int N, int BN){
  constexpr int STAGEB = CP4*256*16;
  __shared__ char smem[STAGEB + 1024 + BUFSZ*512*4 + BUFSZ*512];
  float4* scoord = (float4*)smem;                                   // [256*CP4]
  float*  sxx    = (float*)(smem + STAGEB);                         // [256]
  float*  pdbuf  = (float*)(smem + STAGEB + 1024);                  // [BUFSZ*512]
  unsigned char* idxbuf = (unsigned char*)(smem + STAGEB + 1024 + BUFSZ*512*4);

  const int gpb = N >> 9;                    // 512-query groups per batch
  const int gq  = blockIdx.x >> 4;
  const int s   = blockIdx.x & (NSLICE-1);
  const int b   = gq / gpb;
  const int n0  = (gq - b*gpb) << 9;
  const int tid = threadIdx.x;
  const int bN  = b*N;
  const int m0  = s << 8;
  const float4* fb = reinterpret_cast<const float4*>(feat);

  // ---- stage slice candidates + xx (coalesced) ----
  {
    const float4* src = fb + (size_t)(bN + m0)*CP4;
    for (int j = tid; j < 256*CP4; j += 512) scoord[j] = src[j];
    if (tid < 256) sxx[tid] = xx[bN + m0 + tid];
  }
  float4 own[CP4];
  #pragma unroll
  for (int i=0;i<CP4;++i) own[i] = fb[(size_t)(bN + n0 + tid)*CP4 + i];
  __syncthreads();

  auto pdof = [&](int j)->float{             // j in [0,256): slice-local
    const float4* cp = scoord + j*CP4;       // LDS broadcast (wave-uniform addr)
    float d0=0.f, d1=0.f;
    #pragma unroll
    for (int i=0;i<CP4;++i){
      float4 c = cp[i];
      d0 = fmaf(own[i].x,c.x,d0);
      d1 = fmaf(own[i].y,c.y,d1);
      d0 = fmaf(own[i].z,c.z,d0);
      d1 = fmaf(own[i].w,c.w,d1);
    }
    return fmaf(2.f, d0+d1, -sxx[j]);
  };

  unsigned long long arr[ARRSZ];             // sorted descending at all times
  float thresh;
  int cnt = 0;

  // ---- seed: exact sorted top-32 of first 32 candidates (genuine valley-32) ----
  {
    unsigned long long bv1[16], bv2[16];
    #pragma unroll
    for (int j=0;j<16;++j){
      float pd = pdof(j);
      bv1[j] = ((unsigned long long)ordf(pd)<<32) | (unsigned)((m0+j) ^ 0xFFFF);
    }
    sort16_desc(bv1);
    #pragma unroll
    for (int j=0;j<16;++j){
      float pd = pdof(16+j);
      bv2[j] = ((unsigned long long)ordf(pd)<<32) | (unsigned)((m0+16+j) ^ 0xFFFF);
    }
    sort16_desc(bv2);
    #pragma unroll
    for (int i=0;i<ARRSZ;++i) arr[i] = (i<16) ? bv1[i] : bv2[31-i];
    bmerge32_desc(arr);
    thresh = unordf((unsigned)(arr[K_NN-1]>>32));
  }

  auto do_flush = [&](){
    unsigned long long bv[16];
    #pragma unroll
    for (int q=0;q<16;++q){
      unsigned long long key = 0ull;
      if (q<BUFSZ){
        float pd = pdbuf[q*512 + tid];
        unsigned j8 = idxbuf[q*512 + tid];
        key = ((unsigned long long)ordf(pd)<<32) | (unsigned)((m0+(int)j8) ^ 0xFFFF);
      }
      bv[q] = (q < cnt) ? key : 0ull;
    }
    sort16_desc(bv);
    #pragma unroll
    for (int i=16;i<32;++i){
      unsigned long long t2 = bv[31-i];
      arr[i] = arr[i] > t2 ? arr[i] : t2;
    }
    bmerge32_desc(arr);                      // valley-32 -> sorted desc (proven)
    thresh = unordf((unsigned)(arr[K_NN-1]>>32));
    cnt = 0;
  };

  // ---- main loop: chunks of 4 candidates, j = 32..255 ----
  constexpr int C = 4;
  for (int ch=0; ch<(256-32)/C; ++ch){
    const int jc = 32 + ch*C;
    float pdv[C];
    #pragma unroll
    for (int j=0;j<C;++j) pdv[j] = pdof(jc+j);
    #pragma unroll
    for (int j=0;j<C;++j){
      if (pdv[j] >= thresh){
        pdbuf[cnt*512 + tid]  = pdv[j];
        idxbuf[cnt*512 + tid] = (unsigned char)(jc+j);
        ++cnt;
      }
    }
    if (__ballot(cnt >= BUFSZ-C)) do_flush();   // pre-chunk cnt <= 7 -> max fill 11
  }
  if (__ballot(cnt > 0)) do_flush();

  // ---- emit sorted top-20 (TRANSPOSED layout: [s][k][q], coalesced) ----
  {
    const int q = bN + n0 + tid;               // global query id
    #pragma unroll
    for (int k=0;k<K_NN;++k){
      unsigned m = ((unsigned)arr[k] ^ 0xFFFFu) & 0xFFFFu;   // true global idx
      pd32[((size_t)s*K_NN + k)*BN + q] = (unsigned)(arr[k]>>32);
      pi8 [((size_t)s*K_NN + k)*BN + q] = (unsigned char)(m & 255u);
    }
  }
}

// ---------------- fused: 16-way merge of slice lists + ctr half matmul ----------------
template<int CIN,int CP4,int O>
__global__ __launch_bounds__(256) void merge_ctr_kernel(const unsigned* __restrict__ pd32,
                                                        const unsigned char* __restrict__ pi8,
                                                        int* __restrict__ idx_out,
                                                        const float* __restrict__ feat,
                                                        const float* __restrict__ W,
                                                        float* __restrict__ h0, int total){
  int i = blockIdx.x*256 + threadIdx.x;
  if (i>=total) return;
  // ---- 16-way merge of sorted slice lists (transposed layout reads) ----
  {
    auto keyat = [&](int s, int pos)->unsigned long long{
      unsigned d  = pd32[((size_t)s*K_NN + pos)*total + i];
      unsigned j8 = pi8 [((size_t)s*K_NN + pos)*total + i];
      unsigned m = (unsigned)(s*256) + j8;
      return ((unsigned long long)d<<16) | (unsigned)((m ^ 0xFFFF) & 0xFFFFu);
    };
    unsigned long long heads[NSLICE];
    #pragma unroll
    for (int j=0;j<NSLICE;++j) heads[j] = keyat(j, 0);
    unsigned long long pk0=0ull, pk1=0ull;   // 8x8-bit counters each
    int* op = idx_out + (size_t)i*K_NN;
    for (int k=0;k<K_NN;++k){
      unsigned long long best=heads[0]; int bj=0;
      #pragma unroll
      for (int j=1;j<NSLICE;++j){ bool gg=heads[j]>best; best=gg?heads[j]:best; bj=gg?j:bj; }
      op[k] = (int)(((unsigned)best & 0xFFFFu) ^ 0xFFFFu);
      unsigned pos;
      if (bj < 8){ pos = (unsigned)((pk0>>(bj*8))&0xFFull)+1u; pk0 += (1ull<<(bj*8)); }
      else       { pos = (unsigned)((pk1>>((bj-8)*8))&0xFFull)+1u; pk1 += (1ull<<((bj-8)*8)); }
      unsigned long long nv = 0ull;
      if (pos < K_NN) nv = keyat(bj, (int)pos);
      #pragma unroll
      for (int j=0;j<NSLICE;++j) heads[j]=(j==bj)?nv:heads[j];
    }
  }
  // ---- ctr half of the edge matmul ----
  {
    const float4* p = reinterpret_cast<const float4*>(feat)+(size_t)i*CP4;
    float c[CP4*4];
    #pragma unroll
    for (int j=0;j<CP4;++j){
      float4 v=p[j];
      c[4*j+0]=v.x; c[4*j+1]=v.y; c[4*j+2]=v.z; c[4*j+3]=v.w;
    }
    float* hp = h0 + (size_t)i*O;
    #pragma unroll
    for (int o=0;o<O;++o){
      const float* wr = W + o*(2*CIN) + CIN;   // uniform -> s_load
      float a=0.f;
      #pragma unroll
      for (int cc=0;cc<CIN;++cc) a=fmaf(wr[cc],c[cc],a);
      hp[o]=a;
    }
  }
}

// ---------------- edge conv: thread per (point, neighbor); fused next-layer xx ----------------
template<int CIN,int CP4,int O>
__global__ __launch_bounds__(320) void edge_kernel(const float* __restrict__ feat,
      const int* __restrict__ knn_idx, const float* __restrict__ h0,
      const float* __restrict__ W, const float* __restrict__ g, const float* __restrict__ bb,
      float* __restrict__ outf, float* __restrict__ xxo, int N){
  __shared__ unsigned ob[16*O];
  const int t = threadIdx.x;
  const int p = t/K_NN, k = t - p*K_NN;
  const int b = blockIdx.y;
  const int n = blockIdx.x*16 + p;
  const int bN = b*N;
  for (int v=t; v<16*O; v+=320) ob[v]=0u;
  __syncthreads();
  const int m = knn_idx[(size_t)(bN+n)*K_NN + k];
  const float4* fb = reinterpret_cast<const float4*>(feat);
  float d[CP4*4];
  #pragma unroll
  for (int j=0;j<CP4;++j){
    float4 a = fb[(size_t)(bN+m)*CP4+j];
    float4 c = fb[(size_t)(bN+n)*CP4+j];
    d[4*j+0]=a.x-c.x; d[4*j+1]=a.y-c.y; d[4*j+2]=a.z-c.z; d[4*j+3]=a.w-c.w;
  }
  float h[O];
  const float4* hp = reinterpret_cast<const float4*>(h0 + (size_t)(bN+n)*O);
  #pragma unroll
  for (int j=0;j<O/4;++j){ float4 v=hp[j]; h[4*j]=v.x; h[4*j+1]=v.y; h[4*j+2]=v.z; h[4*j+3]=v.w; }
  #pragma unroll
  for (int o=0;o<O;++o){
    const float* wr = W + o*(2*CIN);          // uniform -> s_load
    float a=h[o];
    #pragma unroll
    for (int cc=0;cc<CIN;++cc) a=fmaf(wr[cc],d[cc],a);
    h[o]=a;
  }
  float mean=0.f;
  #pragma unroll
  for (int o=0;o<O;++o) mean+=h[o];
  mean *= (1.f/(float)O);
  float var=0.f;
  #pragma unroll
  for (int o=0;o<O;++o){ float dd=h[o]-mean; var=fmaf(dd,dd,var); }
  var *= (1.f/(float)O);
  const float r = rsqrtf(var+LN_EPS);
  #pragma unroll
  for (int o=0;o<O;++o){
    float hv = (h[o]-mean)*r*g[o]+bb[o];
    hv = (hv>=0.f)? hv : NEG_SLOPE*hv;
    atomicMax(&ob[p*O+o], ordf(hv));
  }
  __syncthreads();
  for (int v=t; v<16*O; v+=320){
    int pp=v/O, oo=v-pp*O;
    outf[(size_t)(bN+blockIdx.x*16+pp)*O+oo]=unordf(ob[v]);
  }
  if (t < 16){
    float s=0.f;
    for (int oo=0;oo<O;++oo){
      float f = unordf(ob[t*O+oo]);
      s = fmaf(f,f,s);
    }
    xxo[bN + blockIdx.x*16 + t] = s;
  }
}

// ---------------- global max pool over points ----------------
__global__ __launch_bounds__(256) void final_max_kernel(const float* __restrict__ x1,
    const float* __restrict__ x2, const float* __restrict__ x3, const float* __restrict__ x4,
    float* __restrict__ out, int N){
  __shared__ float red[256];
  const int L=blockIdx.x, b=blockIdx.y;
  const float* f; int O, off;
  if (L==0){f=x1;O=16;off=0;}
  else if (L==1){f=x2;O=16;off=16;}
  else if (L==2){f=x3;O=32;off=32;}
  else {f=x4;O=64;off=64;}
  const int t=threadIdx.x;
  const int c=t%O, s=t/O, S=256/O;
  float acc=-3.402823466e38f;
  for (int n=s;n<N;n+=S) acc=fmaxf(acc, f[(size_t)(b*N+n)*O+c]);
  red[t]=acc; __syncthreads();
  if (t<O){
    float a=red[t];
    for (int ss=1;ss<S;++ss) a=fmaxf(a,red[ss*O+t]);
    out[b*128+off+t]=a;
  }
}

extern "C" void kernel_launch(void* const* d_in, const int* in_sizes, int n_in,
                              void* d_out, int out_size, void* d_ws, size_t ws_size,
                              hipStream_t stream){
  const float* x  = (const float*)d_in[0];
  const float* W1 = (const float*)d_in[1];  const float* g1=(const float*)d_in[2];  const float* b1=(const float*)d_in[3];
  const float* W2 = (const float*)d_in[4];  const float* g2=(const float*)d_in[5];  const float* b2=(const float*)d_in[6];
  const float* W3 = (const float*)d_in[7];  const float* g3=(const float*)d_in[8];  const float* b3=(const float*)d_in[9];
  const float* W4 = (const float*)d_in[10]; const float* g4=(const float*)d_in[11]; const float* b4=(const float*)d_in[12];
  float* out=(float*)d_out;
  const int B=4;
  const int N=in_sizes[0]/(3*B);
  const int BN=B*N;

  char* ws=(char*)d_ws;
  size_t off=0;
  auto alloc=[&](size_t bytes)->void*{ void* p=ws+off; off=(off+bytes+255)&~(size_t)255; return p; };
  float* xn =(float*)alloc((size_t)BN*4*4);
  float* x1 =(float*)alloc((size_t)BN*16*4);
  float* x2 =(float*)alloc((size_t)BN*16*4);
  float* x3 =(float*)alloc((size_t)BN*32*4);
  float* x4 =(float*)alloc((size_t)BN*64*4);
  float* xxb=(float*)alloc((size_t)BN*4);
  int*   knn=(int*)  alloc((size_t)BN*K_NN*4);
  float* h0 =(float*)alloc((size_t)BN*64*4);
  unsigned*      pd32=(unsigned*)     alloc((size_t)NSLICE*BN*K_NN*4);  // 21.0 MB
  unsigned char* pi8 =(unsigned char*)alloc((size_t)NSLICE*BN*K_NN);    //  5.2 MB

  dim3 pb((BN+255)/256), tb(256);
  dim3 kb((BN/512)*NSLICE), kt(512);
  dim3 eb(N/16,B), et(320);

  normalize_kernel<<<dim3(B),dim3(1024),0,stream>>>(x,xn,xxb,N);

  // layer 1: 3 -> 16
  knn_kernel<1><<<kb,kt,0,stream>>>(xn,xxb,pd32,pi8,N,BN);
  merge_ctr_kernel<3,1,16><<<pb,tb,0,stream>>>(pd32,pi8,knn,xn,W1,h0,BN);
  edge_kernel<3,1,16><<<eb,et,0,stream>>>(xn,knn,h0,W1,g1,b1,x1,xxb,N);

  // layer 2: 16 -> 16
  knn_kernel<4><<<kb,kt,0,stream>>>(x1,xxb,pd32,pi8,N,BN);
  merge_ctr_kernel<16,4,16><<<pb,tb,0,stream>>>(pd32,pi8,knn,x1,W2,h0,BN);
  edge_kernel<16,4,16><<<eb,et,0,stream>>>(x1,knn,h0,W2,g2,b2,x2,xxb,N);

  // layer 3: 16 -> 32
  knn_kernel<4><<<kb,kt,0,stream>>>(x2,xxb,pd32,pi8,N,BN);
  merge_ctr_kernel<16,4,32><<<pb,tb,0,stream>>>(pd32,pi8,knn,x2,W3,h0,BN);
  edge_kernel<16,4,32><<<eb,et,0,stream>>>(x2,knn,h0,W3,g3,b3,x3,xxb,N);

  // layer 4: 32 -> 64
  knn_kernel<8><<<kb,kt,0,stream>>>(x3,xxb,pd32,pi8,N,BN);
  merge_ctr_kernel<32,8,64><<<pb,tb,0,stream>>>(pd32,pi8,knn,x3,W4,h0,BN);
  edge_kernel<32,8,64><<<eb,et,0,stream>>>(x3,knn,h0,W4,g4,b4,x4,xxb,N);

  final_max_kernel<<<dim3(4,B),dim3(256),0,stream>>>(x1,x2,x3,x4,out,N);
}

// Round 14
// 1004.765 us; speedup vs baseline: 1.3956x; 1.3713x over previous
//
#include <hip/hip_runtime.h>

#define K_NN 20
#define LN_EPS 1e-5f
#define NEG_SLOPE 0.2f
#define BUFSZ 15
#define ARRSZ 32

__device__ __forceinline__ unsigned ordf(float f){
  unsigned u = __float_as_uint(f);
  return u ^ (((unsigned)((int)u >> 31)) | 0x80000000u);
}
__device__ __forceinline__ float unordf(unsigned u){
  unsigned m = ((int)u < 0) ? 0x80000000u : 0xFFFFFFFFu;
  return __uint_as_float(u ^ m);
}

__device__ __forceinline__ void ce_desc(unsigned long long &a, unsigned long long &b){
  unsigned long long mx = a>b ? a : b;
  unsigned long long mn = a>b ? b : a;
  a = mx; b = mn;
}

__device__ __forceinline__ void sort16_desc(unsigned long long (&v)[16]){
  #pragma unroll
  for (int k=2;k<=16;k<<=1){
    #pragma unroll
    for (int j=k>>1;j>0;j>>=1){
      #pragma unroll
      for (int i=0;i<16;++i){
        int l = i ^ j;
        if (l > i){
          if ((i & k) == 0) ce_desc(v[i], v[l]);
          else              ce_desc(v[l], v[i]);
        }
      }
    }
  }
}

// full 32-wide bitonic merge cleanup (valid for any genuine 32-long bitonic
// sequence, e.g. the valley produced by the max-split of two desc lists).
// Round-8 lesson: never prune with virtual -inf pads (not bitonic).
__device__ __forceinline__ void bmerge32_desc(unsigned long long (&v)[32]){
  #pragma unroll
  for (int d=16; d>0; d>>=1){
    #pragma unroll
    for (int i=0;i<32;++i){
      if ((i & d) == 0) ce_desc(v[i], v[i|d]);
    }
  }
}

// ---------------- normalize (+ fused layer-1 xx) ----------------
__global__ __launch_bounds__(1024) void normalize_kernel(const float* __restrict__ x,
                                                         float* __restrict__ xn,
                                                         float* __restrict__ xxo, int N){
  __shared__ float red[1024];
  __shared__ float ms[4];
  const int b = blockIdx.x;
  const int t = threadIdx.x;
  const float* xb = x + (size_t)b*3*N;
  float s0=0.f,s1=0.f,s2=0.f;
  for (int n=t;n<N;n+=1024){ s0+=xb[n]; s1+=xb[N+n]; s2+=xb[2*N+n]; }
  red[t]=s0; __syncthreads();
  for(int o=512;o>0;o>>=1){ if(t<o) red[t]+=red[t+o]; __syncthreads(); }
  if(!t) ms[0]=red[0]/(float)N; __syncthreads();
  red[t]=s1; __syncthreads();
  for(int o=512;o>0;o>>=1){ if(t<o) red[t]+=red[t+o]; __syncthreads(); }
  if(!t) ms[1]=red[0]/(float)N; __syncthreads();
  red[t]=s2; __syncthreads();
  for(int o=512;o>0;o>>=1){ if(t<o) red[t]+=red[t+o]; __syncthreads(); }
  if(!t) ms[2]=red[0]/(float)N; __syncthreads();
  const float m0=ms[0], m1=ms[1], m2=ms[2];
  float mx=0.f;
  for (int n=t;n<N;n+=1024){
    float a=xb[n]-m0, c1=xb[N+n]-m1, c2=xb[2*N+n]-m2;
    mx = fmaxf(mx, a*a+c1*c1+c2*c2);
  }
  red[t]=mx; __syncthreads();
  for(int o=512;o>0;o>>=1){ if(t<o) red[t]=fmaxf(red[t],red[t+o]); __syncthreads(); }
  if(!t) ms[3]=sqrtf(red[0])+1e-8f; __syncthreads();
  const float md=ms[3];
  for (int n=t;n<N;n+=1024){
    float a=xb[n]-m0, c1=xb[N+n]-m1, c2=xb[2*N+n]-m2;
    float4 v; v.x=a/md; v.y=c1/md; v.z=c2/md; v.w=0.f;
    reinterpret_cast<float4*>(xn)[(size_t)b*N+n]=v;
    float s=0.f;
    s=fmaf(v.x,v.x,s); s=fmaf(v.y,v.y,s); s=fmaf(v.z,v.z,s); s=fmaf(v.w,v.w,s);
    xxo[b*N+n]=s;
  }
}

// ---------------- KNN: split-2 candidate space, 8 waves/block ----------------
// Proven round-11 core: s_load candidate path (coords in SGPRs — keeps the
// u64 selection state out of scratch; the r12/r13 LDS-staged variant spilled
// and paid 1.25 GB/dispatch of HBM scratch traffic). Seed + float-threshold +
// chunked hot loop + LDS-buffered flush (sort16 + split + bmerge32).
template<int CP4>
__global__ __launch_bounds__(512,4) void knn_kernel(const float* __restrict__ feat,
                                                    const float* __restrict__ xx,
                                                    unsigned* __restrict__ pd32,
                                                    unsigned short* __restrict__ pi16,
                                                    int N){
  __shared__ unsigned long long sbuf[BUFSZ*512];   // 61440 B, re-aliased for merge phase
  const int ng = N>>6;
  const int s  = blockIdx.x & 1;
  const int gi = blockIdx.x >> 1;
  const int b  = gi / ng;
  const int n0 = (gi % ng) << 6;
  const int tid = threadIdx.x;
  const int lane = tid & 63;
  const int w = __builtin_amdgcn_readfirstlane(tid >> 6);
  const int bN = b*N;
  const int n = n0 + lane;
  const float4* fb = reinterpret_cast<const float4*>(feat);
  float4 own[CP4];
  #pragma unroll
  for (int i=0;i<CP4;++i) own[i] = fb[(size_t)(bN+n)*CP4 + i];

  auto pdof = [&](int m)->float{
    const float4* cp = fb + (size_t)(bN+m)*CP4;   // wave-uniform -> s_load
    float d0=0.f, d1=0.f;
    #pragma unroll
    for (int i=0;i<CP4;++i){
      float4 c = cp[i];
      d0 = fmaf(own[i].x,c.x,d0);
      d1 = fmaf(own[i].y,c.y,d1);
      d0 = fmaf(own[i].z,c.z,d0);
      d1 = fmaf(own[i].w,c.w,d1);
    }
    return fmaf(2.f, d0+d1, -xx[bN+m]);      // -xxn dropped (row-constant shift)
  };

  const int m0 = s*(N>>1) + w*(N>>4);        // slice = N/16 per wave

  unsigned long long arr[ARRSZ];             // sorted descending at all times
  float thresh;                              // float (shifted) distance of current 20th best
  int cnt = 0;

  // ---- seed: exact sorted top-32 of first 32 candidates (genuine valley-32) ----
  {
    unsigned long long bv1[16], bv2[16];
    #pragma unroll
    for (int j=0;j<16;++j){
      float pd = pdof(m0+j);
      bv1[j] = ((unsigned long long)ordf(pd)<<32) | (unsigned)((m0+j) ^ 0xFFFF);
    }
    sort16_desc(bv1);
    #pragma unroll
    for (int j=0;j<16;++j){
      float pd = pdof(m0+16+j);
      bv2[j] = ((unsigned long long)ordf(pd)<<32) | (unsigned)((m0+16+j) ^ 0xFFFF);
    }
    sort16_desc(bv2);
    #pragma unroll
    for (int i=0;i<ARRSZ;++i) arr[i] = (i<16) ? bv1[i] : bv2[31-i];
    bmerge32_desc(arr);
    thresh = unordf((unsigned)(arr[K_NN-1]>>32));   // exact 20th best so far
  }

  auto do_flush = [&](){
    unsigned long long bv[16];
    #pragma unroll
    for (int q=0;q<16;++q){
      unsigned long long v = (q<BUFSZ) ? sbuf[q*512 + tid] : 0ull;
      bv[q] = (q < cnt) ? v : 0ull;
    }
    sort16_desc(bv);
    #pragma unroll
    for (int i=16;i<32;++i){
      unsigned long long t2 = bv[31-i];
      arr[i] = arr[i] > t2 ? arr[i] : t2;
    }
    bmerge32_desc(arr);                      // valley-32 -> sorted desc (proven)
    thresh = unordf((unsigned)(arr[K_NN-1]>>32));
    cnt = 0;
  };

  // ---- main loop: chunks of C candidates (batched loads -> ILP) ----
  constexpr int C = (CP4==1) ? 8 : 4;
  const int nchunks = ((N>>4) - 32) / C;
  for (int ch=0; ch<nchunks; ++ch){
    const int mc = m0 + 32 + ch*C;
    float pdv[C];
    #pragma unroll
    for (int j=0;j<C;++j) pdv[j] = pdof(mc+j);
    #pragma unroll
    for (int j=0;j<C;++j){
      if (pdv[j] >= thresh){
        sbuf[cnt*512 + tid] =
          ((unsigned long long)ordf(pdv[j])<<32) | (unsigned)((mc+j) ^ 0xFFFF);
        ++cnt;
      }
    }
    if (__ballot(cnt >= BUFSZ-C)) do_flush();   // pre-chunk cnt <= BUFSZ-C-1 -> max fill 14
  }
  if (__ballot(cnt > 0)) do_flush();

  __syncthreads();
  // re-alias LDS for the 8-list block merge.
  // lkh = FULL 32-bit ordered distance (arr>>32); lki = 16-bit idx^0xFFFF.
  unsigned* lkh = (unsigned*)sbuf;                              // 8*20*64*4 = 40960
  unsigned short* lki = (unsigned short*)(((char*)sbuf)+40960); // 8*20*64*2 = 20480
  #pragma unroll
  for (int i=0;i<K_NN;++i){
    lkh[((w*K_NN+i)<<6)+lane] = (unsigned)(arr[i]>>32);
    lki[((w*K_NN+i)<<6)+lane] = (unsigned short)(arr[i]&0xFFFFu);
  }
  __syncthreads();
  if (tid < 64){
    const int l = tid;
    unsigned long long heads[8];
    #pragma unroll
    for (int j=0;j<8;++j){
      int q0=((j*K_NN)<<6)+l;
      heads[j]=((unsigned long long)lkh[q0]<<16)|(unsigned long long)lki[q0];
    }
    unsigned long long pk=0ull;      // 8 x 5-bit counters
    const size_t pbase = ((size_t)(bN+n0+l)*2 + s)*K_NN;
    for (int kk=0;kk<K_NN;++kk){
      unsigned long long best=heads[0]; int bj=0;
      #pragma unroll
      for (int j=1;j<8;++j){ bool gg=heads[j]>best; best=gg?heads[j]:best; bj=gg?j:bj; }
      pd32[pbase+kk] = (unsigned)(best>>16);          // full ordered distance
      pi16[pbase+kk] = (unsigned short)(best & 0xFFFFu);
      unsigned pos = (unsigned)((pk>>(bj*5))&0x1Ful)+1u;
      pk += (1ull<<(bj*5));
      unsigned long long nv = 0ull;
      if (pos<K_NN){
        int q1=((bj*K_NN+(int)pos)<<6)+l;
        nv=((unsigned long long)lkh[q1]<<16)|(unsigned long long)lki[q1];
      }
      #pragma unroll
      for (int j=0;j<8;++j) heads[j]=(j==bj)?nv:heads[j];
    }
  }
}

// ---------------- fused: merge the two half top-20 lists + ctr half matmul ----------------
template<int CIN,int CP4,int O>
__global__ __launch_bounds__(256) void merge_ctr_kernel(const unsigned* __restrict__ pd32,
                                                        const unsigned short* __restrict__ pi16,
                                                        int* __restrict__ idx_out,
                                                        const float* __restrict__ feat,
                                                        const float* __restrict__ W,
                                                        float* __restrict__ h0, int total){
  int i = blockIdx.x*256 + threadIdx.x;
  if (i>=total) return;
  // ---- 2-way merge of sorted half-lists ----
  {
    const unsigned* d0 = pd32 + (size_t)i*2*K_NN;
    const unsigned short* i0 = pi16 + (size_t)i*2*K_NN;
    const unsigned* d1 = d0 + K_NN;
    const unsigned short* i1 = i0 + K_NN;
    int a=0, c=0;
    int* op = idx_out + (size_t)i*K_NN;
    #pragma unroll 4
    for (int k=0;k<K_NN;++k){
      unsigned long long k0 = ((unsigned long long)d0[a]<<16) | i0[a];
      unsigned long long k1 = ((unsigned long long)d1[c]<<16) | i1[c];
      bool t = k0 > k1;
      unsigned long long best = t ? k0 : k1;
      op[k] = (int)(((unsigned)best & 0xFFFFu) ^ 0xFFFFu);
      a += t; c += !t;
    }
  }
  // ---- ctr half of the edge matmul ----
  {
    const float4* p = reinterpret_cast<const float4*>(feat)+(size_t)i*CP4;
    float c[CP4*4];
    #pragma unroll
    for (int j=0;j<CP4;++j){
      float4 v=p[j];
      c[4*j+0]=v.x; c[4*j+1]=v.y; c[4*j+2]=v.z; c[4*j+3]=v.w;
    }
    float* hp = h0 + (size_t)i*O;
    #pragma unroll
    for (int o=0;o<O;++o){
      const float* wr = W + o*(2*CIN) + CIN;   // uniform -> s_load
      float a=0.f;
      #pragma unroll
      for (int cc=0;cc<CIN;++cc) a=fmaf(wr[cc],c[cc],a);
      hp[o]=a;
    }
  }
}

// ---------------- edge conv: thread per (point, neighbor); fused next-layer xx ----------------
template<int CIN,int CP4,int O>
__global__ __launch_bounds__(320) void edge_kernel(const float* __restrict__ feat,
      const int* __restrict__ knn_idx, const float* __restrict__ h0,
      const float* __restrict__ W, const float* __restrict__ g, const float* __restrict__ bb,
      float* __restrict__ outf, float* __restrict__ xxo, int N){
  __shared__ unsigned ob[16*O];
  const int t = threadIdx.x;
  const int p = t/K_NN, k = t - p*K_NN;
  const int b = blockIdx.y;
  const int n = blockIdx.x*16 + p;
  const int bN = b*N;
  for (int v=t; v<16*O; v+=320) ob[v]=0u;
  __syncthreads();
  const int m = knn_idx[(size_t)(bN+n)*K_NN + k];
  const float4* fb = reinterpret_cast<const float4*>(feat);
  float d[CP4*4];
  #pragma unroll
  for (int j=0;j<CP4;++j){
    float4 a = fb[(size_t)(bN+m)*CP4+j];
    float4 c = fb[(size_t)(bN+n)*CP4+j];
    d[4*j+0]=a.x-c.x; d[4*j+1]=a.y-c.y; d[4*j+2]=a.z-c.z; d[4*j+3]=a.w-c.w;
  }
  float h[O];
  const float4* hp = reinterpret_cast<const float4*>(h0 + (size_t)(bN+n)*O);
  #pragma unroll
  for (int j=0;j<O/4;++j){ float4 v=hp[j]; h[4*j]=v.x; h[4*j+1]=v.y; h[4*j+2]=v.z; h[4*j+3]=v.w; }
  #pragma unroll
  for (int o=0;o<O;++o){
    const float* wr = W + o*(2*CIN);          // uniform -> s_load
    float a=h[o];
    #pragma unroll
    for (int cc=0;cc<CIN;++cc) a=fmaf(wr[cc],d[cc],a);
    h[o]=a;
  }
  float mean=0.f;
  #pragma unroll
  for (int o=0;o<O;++o) mean+=h[o];
  mean *= (1.f/(float)O);
  float var=0.f;
  #pragma unroll
  for (int o=0;o<O;++o){ float dd=h[o]-mean; var=fmaf(dd,dd,var); }
  var *= (1.f/(float)O);
  const float r = rsqrtf(var+LN_EPS);
  #pragma unroll
  for (int o=0;o<O;++o){
    float hv = (h[o]-mean)*r*g[o]+bb[o];
    hv = (hv>=0.f)? hv : NEG_SLOPE*hv;
    atomicMax(&ob[p*O+o], ordf(hv));
  }
  __syncthreads();
  for (int v=t; v<16*O; v+=320){
    int pp=v/O, oo=v-pp*O;
    outf[(size_t)(bN+blockIdx.x*16+pp)*O+oo]=unordf(ob[v]);
  }
  // fused xx for the next layer (bitwise-identical fmaf chain)
  if (t < 16){
    float s=0.f;
    for (int oo=0;oo<O;++oo){
      float f = unordf(ob[t*O+oo]);
      s = fmaf(f,f,s);
    }
    xxo[bN + blockIdx.x*16 + t] = s;
  }
}

// ---------------- global max pool over points ----------------
__global__ __launch_bounds__(256) void final_max_kernel(const float* __restrict__ x1,
    const float* __restrict__ x2, const float* __restrict__ x3, const float* __restrict__ x4,
    float* __restrict__ out, int N){
  __shared__ float red[256];
  const int L=blockIdx.x, b=blockIdx.y;
  const float* f; int O, off;
  if (L==0){f=x1;O=16;off=0;}
  else if (L==1){f=x2;O=16;off=16;}
  else if (L==2){f=x3;O=32;off=32;}
  else {f=x4;O=64;off=64;}
  const int t=threadIdx.x;
  const int c=t%O, s=t/O, S=256/O;
  float acc=-3.402823466e38f;
  for (int n=s;n<N;n+=S) acc=fmaxf(acc, f[(size_t)(b*N+n)*O+c]);
  red[t]=acc; __syncthreads();
  if (t<O){
    float a=red[t];
    for (int ss=1;ss<S;++ss) a=fmaxf(a,red[ss*O+t]);
    out[b*128+off+t]=a;
  }
}

extern "C" void kernel_launch(void* const* d_in, const int* in_sizes, int n_in,
                              void* d_out, int out_size, void* d_ws, size_t ws_size,
                              hipStream_t stream){
  const float* x  = (const float*)d_in[0];
  const float* W1 = (const float*)d_in[1];  const float* g1=(const float*)d_in[2];  const float* b1=(const float*)d_in[3];
  const float* W2 = (const float*)d_in[4];  const float* g2=(const float*)d_in[5];  const float* b2=(const float*)d_in[6];
  const float* W3 = (const float*)d_in[7];  const float* g3=(const float*)d_in[8];  const float* b3=(const float*)d_in[9];
  const float* W4 = (const float*)d_in[10]; const float* g4=(const float*)d_in[11]; const float* b4=(const float*)d_in[12];
  float* out=(float*)d_out;
  const int B=4;
  const int N=in_sizes[0]/(3*B);
  const int BN=B*N;

  char* ws=(char*)d_ws;
  size_t off=0;
  auto alloc=[&](size_t bytes)->void*{ void* p=ws+off; off=(off+bytes+255)&~(size_t)255; return p; };
  float* xn =(float*)alloc((size_t)BN*4*4);
  float* x1 =(float*)alloc((size_t)BN*16*4);
  float* x2 =(float*)alloc((size_t)BN*16*4);
  float* x3 =(float*)alloc((size_t)BN*32*4);
  float* x4 =(float*)alloc((size_t)BN*64*4);
  float* xxb=(float*)alloc((size_t)BN*4);
  int*   knn=(int*)  alloc((size_t)BN*K_NN*4);
  float* h0 =(float*)alloc((size_t)BN*64*4);
  unsigned*       pd32=(unsigned*)      alloc((size_t)BN*2*K_NN*4);  // own buffer (no h0 alias:
  unsigned short* pi16=(unsigned short*)alloc((size_t)BN*2*K_NN*2);  // merge_ctr writes h0 concurrently)

  dim3 pb((BN+255)/256), tb(256);
  dim3 kb(B*(N/64)*2), kt(512);
  dim3 eb(N/16,B), et(320);

  normalize_kernel<<<dim3(B),dim3(1024),0,stream>>>(x,xn,xxb,N);

  // layer 1: 3 -> 16
  knn_kernel<1><<<kb,kt,0,stream>>>(xn,xxb,pd32,pi16,N);
  merge_ctr_kernel<3,1,16><<<pb,tb,0,stream>>>(pd32,pi16,knn,xn,W1,h0,BN);
  edge_kernel<3,1,16><<<eb,et,0,stream>>>(xn,knn,h0,W1,g1,b1,x1,xxb,N);

  // layer 2: 16 -> 16
  knn_kernel<4><<<kb,kt,0,stream>>>(x1,xxb,pd32,pi16,N);
  merge_ctr_kernel<16,4,16><<<pb,tb,0,stream>>>(pd32,pi16,knn,x1,W2,h0,BN);
  edge_kernel<16,4,16><<<eb,et,0,stream>>>(x1,knn,h0,W2,g2,b2,x2,xxb,N);

  // layer 3: 16 -> 32
  knn_kernel<4><<<kb,kt,0,stream>>>(x2,xxb,pd32,pi16,N);
  merge_ctr_kernel<16,4,32><<<pb,tb,0,stream>>>(pd32,pi16,knn,x2,W3,h0,BN);
  edge_kernel<16,4,32><<<eb,et,0,stream>>>(x2,knn,h0,W3,g3,b3,x3,xxb,N);

  // layer 4: 32 -> 64
  knn_kernel<8><<<kb,kt,0,stream>>>(x3,xxb,pd32,pi16,N);
  merge_ctr_kernel<32,8,64><<<pb,tb,0,stream>>>(pd32,pi16,knn,x3,W4,h0,BN);
  edge_kernel<32,8,64><<<eb,et,0,stream>>>(x3,knn,h0,W4,g4,b4,x4,xxb,N);

  final_max_kernel<<<dim3(4,B),dim3(256),0,stream>>>(x1,x2,x3,x4,out,N);
}

// Round 15
// 907.911 us; speedup vs baseline: 1.5445x; 1.1067x over previous
//
#include <hip/hip_runtime.h>

#define K_NN 20
#define LN_EPS 1e-5f
#define NEG_SLOPE 0.2f
#define BUFSZ 15
#define ARRSZ 32

__device__ __forceinline__ unsigned ordf(float f){
  unsigned u = __float_as_uint(f);
  return u ^ (((unsigned)((int)u >> 31)) | 0x80000000u);
}
__device__ __forceinline__ float unordf(unsigned u){
  unsigned m = ((int)u < 0) ? 0x80000000u : 0xFFFFFFFFu;
  return __uint_as_float(u ^ m);
}

__device__ __forceinline__ void ce_desc(unsigned long long &a, unsigned long long &b){
  unsigned long long mx = a>b ? a : b;
  unsigned long long mn = a>b ? b : a;
  a = mx; b = mn;
}

__device__ __forceinline__ void sort16_desc(unsigned long long (&v)[16]){
  #pragma unroll
  for (int k=2;k<=16;k<<=1){
    #pragma unroll
    for (int j=k>>1;j>0;j>>=1){
      #pragma unroll
      for (int i=0;i<16;++i){
        int l = i ^ j;
        if (l > i){
          if ((i & k) == 0) ce_desc(v[i], v[l]);
          else              ce_desc(v[l], v[i]);
        }
      }
    }
  }
}

// full 32-wide bitonic merge cleanup (valid for any genuine 32-long bitonic
// sequence, e.g. the valley produced by the max-split of two desc lists).
// Round-8 lesson: never prune with virtual -inf pads (not bitonic).
__device__ __forceinline__ void bmerge32_desc(unsigned long long (&v)[32]){
  #pragma unroll
  for (int d=16; d>0; d>>=1){
    #pragma unroll
    for (int i=0;i<32;++i){
      if ((i & d) == 0) ce_desc(v[i], v[i|d]);
    }
  }
}

// ---------------- normalize (+ fused layer-1 xx) ----------------
__global__ __launch_bounds__(1024) void normalize_kernel(const float* __restrict__ x,
                                                         float* __restrict__ xn,
                                                         float* __restrict__ xxo, int N){
  __shared__ float red[1024];
  __shared__ float ms[4];
  const int b = blockIdx.x;
  const int t = threadIdx.x;
  const float* xb = x + (size_t)b*3*N;
  float s0=0.f,s1=0.f,s2=0.f;
  for (int n=t;n<N;n+=1024){ s0+=xb[n]; s1+=xb[N+n]; s2+=xb[2*N+n]; }
  red[t]=s0; __syncthreads();
  for(int o=512;o>0;o>>=1){ if(t<o) red[t]+=red[t+o]; __syncthreads(); }
  if(!t) ms[0]=red[0]/(float)N; __syncthreads();
  red[t]=s1; __syncthreads();
  for(int o=512;o>0;o>>=1){ if(t<o) red[t]+=red[t+o]; __syncthreads(); }
  if(!t) ms[1]=red[0]/(float)N; __syncthreads();
  red[t]=s2; __syncthreads();
  for(int o=512;o>0;o>>=1){ if(t<o) red[t]+=red[t+o]; __syncthreads(); }
  if(!t) ms[2]=red[0]/(float)N; __syncthreads();
  const float m0=ms[0], m1=ms[1], m2=ms[2];
  float mx=0.f;
  for (int n=t;n<N;n+=1024){
    float a=xb[n]-m0, c1=xb[N+n]-m1, c2=xb[2*N+n]-m2;
    mx = fmaxf(mx, a*a+c1*c1+c2*c2);
  }
  red[t]=mx; __syncthreads();
  for(int o=512;o>0;o>>=1){ if(t<o) red[t]=fmaxf(red[t],red[t+o]); __syncthreads(); }
  if(!t) ms[3]=sqrtf(red[0])+1e-8f; __syncthreads();
  const float md=ms[3];
  for (int n=t;n<N;n+=1024){
    float a=xb[n]-m0, c1=xb[N+n]-m1, c2=xb[2*N+n]-m2;
    float4 v; v.x=a/md; v.y=c1/md; v.z=c2/md; v.w=0.f;
    reinterpret_cast<float4*>(xn)[(size_t)b*N+n]=v;
    float s=0.f;
    s=fmaf(v.x,v.x,s); s=fmaf(v.y,v.y,s); s=fmaf(v.z,v.z,s); s=fmaf(v.w,v.w,s);
    xxo[b*N+n]=s;
  }
}

// ---------------- KNN: split-2 candidate space, 8 waves/block ----------------
// Proven round-11 core (s_load candidate path; seed + float-threshold +
// chunked hot loop + LDS-buffered flush).
template<int CP4>
__global__ __launch_bounds__(512,4) void knn_kernel(const float* __restrict__ feat,
                                                    const float* __restrict__ xx,
                                                    unsigned* __restrict__ pd32,
                                                    unsigned short* __restrict__ pi16,
                                                    int N){
  __shared__ unsigned long long sbuf[BUFSZ*512];   // 61440 B, re-aliased for merge phase
  const int ng = N>>6;
  const int s  = blockIdx.x & 1;
  const int gi = blockIdx.x >> 1;
  const int b  = gi / ng;
  const int n0 = (gi % ng) << 6;
  const int tid = threadIdx.x;
  const int lane = tid & 63;
  const int w = __builtin_amdgcn_readfirstlane(tid >> 6);
  const int bN = b*N;
  const int n = n0 + lane;
  const float4* fb = reinterpret_cast<const float4*>(feat);
  float4 own[CP4];
  #pragma unroll
  for (int i=0;i<CP4;++i) own[i] = fb[(size_t)(bN+n)*CP4 + i];

  auto pdof = [&](int m)->float{
    const float4* cp = fb + (size_t)(bN+m)*CP4;   // wave-uniform -> s_load
    float d0=0.f, d1=0.f;
    #pragma unroll
    for (int i=0;i<CP4;++i){
      float4 c = cp[i];
      d0 = fmaf(own[i].x,c.x,d0);
      d1 = fmaf(own[i].y,c.y,d1);
      d0 = fmaf(own[i].z,c.z,d0);
      d1 = fmaf(own[i].w,c.w,d1);
    }
    return fmaf(2.f, d0+d1, -xx[bN+m]);      // -xxn dropped (row-constant shift)
  };

  const int m0 = s*(N>>1) + w*(N>>4);        // slice = N/16 per wave

  unsigned long long arr[ARRSZ];             // sorted descending at all times
  float thresh;                              // float (shifted) distance of current 20th best
  int cnt = 0;

  // ---- seed: exact sorted top-32 of first 32 candidates (genuine valley-32) ----
  {
    unsigned long long bv1[16], bv2[16];
    #pragma unroll
    for (int j=0;j<16;++j){
      float pd = pdof(m0+j);
      bv1[j] = ((unsigned long long)ordf(pd)<<32) | (unsigned)((m0+j) ^ 0xFFFF);
    }
    sort16_desc(bv1);
    #pragma unroll
    for (int j=0;j<16;++j){
      float pd = pdof(m0+16+j);
      bv2[j] = ((unsigned long long)ordf(pd)<<32) | (unsigned)((m0+16+j) ^ 0xFFFF);
    }
    sort16_desc(bv2);
    #pragma unroll
    for (int i=0;i<ARRSZ;++i) arr[i] = (i<16) ? bv1[i] : bv2[31-i];
    bmerge32_desc(arr);
    thresh = unordf((unsigned)(arr[K_NN-1]>>32));   // exact 20th best so far
  }

  auto do_flush = [&](){
    unsigned long long bv[16];
    #pragma unroll
    for (int q=0;q<16;++q){
      unsigned long long v = (q<BUFSZ) ? sbuf[q*512 + tid] : 0ull;
      bv[q] = (q < cnt) ? v : 0ull;
    }
    sort16_desc(bv);
    #pragma unroll
    for (int i=16;i<32;++i){
      unsigned long long t2 = bv[31-i];
      arr[i] = arr[i] > t2 ? arr[i] : t2;
    }
    bmerge32_desc(arr);                      // valley-32 -> sorted desc (proven)
    thresh = unordf((unsigned)(arr[K_NN-1]>>32));
    cnt = 0;
  };

  // ---- main loop: chunks of C candidates (batched loads -> ILP) ----
  constexpr int C = (CP4==1) ? 8 : 4;
  const int nchunks = ((N>>4) - 32) / C;
  for (int ch=0; ch<nchunks; ++ch){
    const int mc = m0 + 32 + ch*C;
    float pdv[C];
    #pragma unroll
    for (int j=0;j<C;++j) pdv[j] = pdof(mc+j);
    #pragma unroll
    for (int j=0;j<C;++j){
      if (pdv[j] >= thresh){
        sbuf[cnt*512 + tid] =
          ((unsigned long long)ordf(pdv[j])<<32) | (unsigned)((mc+j) ^ 0xFFFF);
        ++cnt;
      }
    }
    if (__ballot(cnt >= BUFSZ-C)) do_flush();   // pre-chunk cnt <= BUFSZ-C-1 -> max fill 14
  }
  if (__ballot(cnt > 0)) do_flush();

  __syncthreads();
  // re-alias LDS for the 8-list block merge.
  // lkh = FULL 32-bit ordered distance (arr>>32); lki = 16-bit idx^0xFFFF.
  unsigned* lkh = (unsigned*)sbuf;                              // 8*20*64*4 = 40960
  unsigned short* lki = (unsigned short*)(((char*)sbuf)+40960); // 8*20*64*2 = 20480
  #pragma unroll
  for (int i=0;i<K_NN;++i){
    lkh[((w*K_NN+i)<<6)+lane] = (unsigned)(arr[i]>>32);
    lki[((w*K_NN+i)<<6)+lane] = (unsigned short)(arr[i]&0xFFFFu);
  }
  __syncthreads();
  if (tid < 64){
    const int l = tid;
    unsigned long long heads[8];
    #pragma unroll
    for (int j=0;j<8;++j){
      int q0=((j*K_NN)<<6)+l;
      heads[j]=((unsigned long long)lkh[q0]<<16)|(unsigned long long)lki[q0];
    }
    unsigned long long pk=0ull;      // 8 x 5-bit counters
    const size_t pbase = ((size_t)(bN+n0+l)*2 + s)*K_NN;
    for (int kk=0;kk<K_NN;++kk){
      unsigned long long best=heads[0]; int bj=0;
      #pragma unroll
      for (int j=1;j<8;++j){ bool gg=heads[j]>best; best=gg?heads[j]:best; bj=gg?j:bj; }
      pd32[pbase+kk] = (unsigned)(best>>16);          // full ordered distance
      pi16[pbase+kk] = (unsigned short)(best & 0xFFFFu);
      unsigned pos = (unsigned)((pk>>(bj*5))&0x1Ful)+1u;
      pk += (1ull<<(bj*5));
      unsigned long long nv = 0ull;
      if (pos<K_NN){
        int q1=((bj*K_NN+(int)pos)<<6)+l;
        nv=((unsigned long long)lkh[q1]<<16)|(unsigned long long)lki[q1];
      }
      #pragma unroll
      for (int j=0;j<8;++j) heads[j]=(j==bj)?nv:heads[j];
    }
  }
}

// ---------------- fused: merge the two half top-20 lists + ctr half matmul ----------------
template<int CIN,int CP4,int O>
__global__ __launch_bounds__(256) void merge_ctr_kernel(const unsigned* __restrict__ pd32,
                                                        const unsigned short* __restrict__ pi16,
                                                        int* __restrict__ idx_out,
                                                        const float* __restrict__ feat,
                                                        const float* __restrict__ W,
                                                        float* __restrict__ h0, int total){
  int i = blockIdx.x*256 + threadIdx.x;
  if (i>=total) return;
  // ---- 2-way merge of sorted half-lists ----
  {
    const unsigned* d0 = pd32 + (size_t)i*2*K_NN;
    const unsigned short* i0 = pi16 + (size_t)i*2*K_NN;
    const unsigned* d1 = d0 + K_NN;
    const unsigned short* i1 = i0 + K_NN;
    int a=0, c=0;
    int* op = idx_out + (size_t)i*K_NN;
    #pragma unroll 4
    for (int k=0;k<K_NN;++k){
      unsigned long long k0 = ((unsigned long long)d0[a]<<16) | i0[a];
      unsigned long long k1 = ((unsigned long long)d1[c]<<16) | i1[c];
      bool t = k0 > k1;
      unsigned long long best = t ? k0 : k1;
      op[k] = (int)(((unsigned)best & 0xFFFFu) ^ 0xFFFFu);
      a += t; c += !t;
    }
  }
  // ---- ctr half of the edge matmul ----
  {
    const float4* p = reinterpret_cast<const float4*>(feat)+(size_t)i*CP4;
    float c[CP4*4];
    #pragma unroll
    for (int j=0;j<CP4;++j){
      float4 v=p[j];
      c[4*j+0]=v.x; c[4*j+1]=v.y; c[4*j+2]=v.z; c[4*j+3]=v.w;
    }
    float* hp = h0 + (size_t)i*O;
    #pragma unroll
    for (int o=0;o<O;++o){
      const float* wr = W + o*(2*CIN) + CIN;   // uniform -> s_load
      float a=0.f;
      #pragma unroll
      for (int cc=0;cc<CIN;++cc) a=fmaf(wr[cc],c[cc],a);
      hp[o]=a;
    }
  }
}

// ---------------- edge conv: thread per (point, neighbor); fused next-layer xx ----------------
// K-max via 4-slot-spread LDS atomicMax (k&3): 20-way same-address contention
// -> 5-way (r14 profile: 1.02e7 LDS conflict cycles per dispatch from the
// single-address version). Max of slot-maxes == global max (exact).
template<int CIN,int CP4,int O>
__global__ __launch_bounds__(320) void edge_kernel(const float* __restrict__ feat,
      const int* __restrict__ knn_idx, const float* __restrict__ h0,
      const float* __restrict__ W, const float* __restrict__ g, const float* __restrict__ bb,
      float* __restrict__ outf, float* __restrict__ xxo, int N){
  __shared__ unsigned ob[16*O*4];
  const int t = threadIdx.x;
  const int p = t/K_NN, k = t - p*K_NN;
  const int b = blockIdx.y;
  const int n = blockIdx.x*16 + p;
  const int bN = b*N;
  for (int v=t; v<16*O*4; v+=320) ob[v]=0u;
  __syncthreads();
  const int m = knn_idx[(size_t)(bN+n)*K_NN + k];
  const float4* fb = reinterpret_cast<const float4*>(feat);
  float d[CP4*4];
  #pragma unroll
  for (int j=0;j<CP4;++j){
    float4 a = fb[(size_t)(bN+m)*CP4+j];
    float4 c = fb[(size_t)(bN+n)*CP4+j];
    d[4*j+0]=a.x-c.x; d[4*j+1]=a.y-c.y; d[4*j+2]=a.z-c.z; d[4*j+3]=a.w-c.w;
  }
  float h[O];
  const float4* hp = reinterpret_cast<const float4*>(h0 + (size_t)(bN+n)*O);
  #pragma unroll
  for (int j=0;j<O/4;++j){ float4 v=hp[j]; h[4*j]=v.x; h[4*j+1]=v.y; h[4*j+2]=v.z; h[4*j+3]=v.w; }
  #pragma unroll
  for (int o=0;o<O;++o){
    const float* wr = W + o*(2*CIN);          // uniform -> s_load
    float a=h[o];
    #pragma unroll
    for (int cc=0;cc<CIN;++cc) a=fmaf(wr[cc],d[cc],a);
    h[o]=a;
  }
  float mean=0.f;
  #pragma unroll
  for (int o=0;o<O;++o) mean+=h[o];
  mean *= (1.f/(float)O);
  float var=0.f;
  #pragma unroll
  for (int o=0;o<O;++o){ float dd=h[o]-mean; var=fmaf(dd,dd,var); }
  var *= (1.f/(float)O);
  const float r = rsqrtf(var+LN_EPS);
  const int slot = k & 3;
  #pragma unroll
  for (int o=0;o<O;++o){
    float hv = (h[o]-mean)*r*g[o]+bb[o];
    hv = (hv>=0.f)? hv : NEG_SLOPE*hv;
    atomicMax(&ob[((p*O+o)<<2) + slot], ordf(hv));
  }
  __syncthreads();
  for (int v=t; v<16*O; v+=320){
    int pp=v/O, oo=v-pp*O;
    unsigned u0=ob[v*4+0], u1=ob[v*4+1], u2=ob[v*4+2], u3=ob[v*4+3];
    unsigned mm = u0>u1?u0:u1; unsigned mm2 = u2>u3?u2:u3;
    mm = mm>mm2?mm:mm2;
    outf[(size_t)(bN+blockIdx.x*16+pp)*O+oo]=unordf(mm);
  }
  // fused xx for the next layer (bitwise-identical fmaf chain)
  if (t < 16){
    float s=0.f;
    for (int oo=0;oo<O;++oo){
      int base=(t*O+oo)*4;
      unsigned u0=ob[base+0], u1=ob[base+1], u2=ob[base+2], u3=ob[base+3];
      unsigned mm = u0>u1?u0:u1; unsigned mm2 = u2>u3?u2:u3;
      mm = mm>mm2?mm:mm2;
      float f = unordf(mm);
      s = fmaf(f,f,s);
    }
    xxo[bN + blockIdx.x*16 + t] = s;
  }
}

// ---------------- global max pool over points ----------------
__global__ __launch_bounds__(256) void final_max_kernel(const float* __restrict__ x1,
    const float* __restrict__ x2, const float* __restrict__ x3, const float* __restrict__ x4,
    float* __restrict__ out, int N){
  __shared__ float red[256];
  const int L=blockIdx.x, b=blockIdx.y;
  const float* f; int O, off;
  if (L==0){f=x1;O=16;off=0;}
  else if (L==1){f=x2;O=16;off=16;}
  else if (L==2){f=x3;O=32;off=32;}
  else {f=x4;O=64;off=64;}
  const int t=threadIdx.x;
  const int c=t%O, s=t/O, S=256/O;
  float acc=-3.402823466e38f;
  for (int n=s;n<N;n+=S) acc=fmaxf(acc, f[(size_t)(b*N+n)*O+c]);
  red[t]=acc; __syncthreads();
  if (t<O){
    float a=red[t];
    for (int ss=1;ss<S;++ss) a=fmaxf(a,red[ss*O+t]);
    out[b*128+off+t]=a;
  }
}

extern "C" void kernel_launch(void* const* d_in, const int* in_sizes, int n_in,
                              void* d_out, int out_size, void* d_ws, size_t ws_size,
                              hipStream_t stream){
  const float* x  = (const float*)d_in[0];
  const float* W1 = (const float*)d_in[1];  const float* g1=(const float*)d_in[2];  const float* b1=(const float*)d_in[3];
  const float* W2 = (const float*)d_in[4];  const float* g2=(const float*)d_in[5];  const float* b2=(const float*)d_in[6];
  const float* W3 = (const float*)d_in[7];  const float* g3=(const float*)d_in[8];  const float* b3=(const float*)d_in[9];
  const float* W4 = (const float*)d_in[10]; const float* g4=(const float*)d_in[11]; const float* b4=(const float*)d_in[12];
  float* out=(float*)d_out;
  const int B=4;
  const int N=in_sizes[0]/(3*B);
  const int BN=B*N;

  char* ws=(char*)d_ws;
  size_t off=0;
  auto alloc=[&](size_t bytes)->void*{ void* p=ws+off; off=(off+bytes+255)&~(size_t)255; return p; };
  float* xn =(float*)alloc((size_t)BN*4*4);
  float* x1 =(float*)alloc((size_t)BN*16*4);
  float* x2 =(float*)alloc((size_t)BN*16*4);
  float* x3 =(float*)alloc((size_t)BN*32*4);
  float* x4 =(float*)alloc((size_t)BN*64*4);
  float* xxb=(float*)alloc((size_t)BN*4);
  int*   knn=(int*)  alloc((size_t)BN*K_NN*4);
  float* h0 =(float*)alloc((size_t)BN*64*4);
  unsigned*       pd32=(unsigned*)      alloc((size_t)BN*2*K_NN*4);  // own buffer (no h0 alias:
  unsigned short* pi16=(unsigned short*)alloc((size_t)BN*2*K_NN*2);  // merge_ctr writes h0 concurrently)

  dim3 pb((BN+255)/256), tb(256);
  dim3 kb(B*(N/64)*2), kt(512);
  dim3 eb(N/16,B), et(320);

  normalize_kernel<<<dim3(B),dim3(1024),0,stream>>>(x,xn,xxb,N);

  // layer 1: 3 -> 16
  knn_kernel<1><<<kb,kt,0,stream>>>(xn,xxb,pd32,pi16,N);
  merge_ctr_kernel<3,1,16><<<pb,tb,0,stream>>>(pd32,pi16,knn,xn,W1,h0,BN);
  edge_kernel<3,1,16><<<eb,et,0,stream>>>(xn,knn,h0,W1,g1,b1,x1,xxb,N);

  // layer 2: 16 -> 16
  knn_kernel<4><<<kb,kt,0,stream>>>(x1,xxb,pd32,pi16,N);
  merge_ctr_kernel<16,4,16><<<pb,tb,0,stream>>>(pd32,pi16,knn,x1,W2,h0,BN);
  edge_kernel<16,4,16><<<eb,et,0,stream>>>(x1,knn,h0,W2,g2,b2,x2,xxb,N);

  // layer 3: 16 -> 32
  knn_kernel<4><<<kb,kt,0,stream>>>(x2,xxb,pd32,pi16,N);
  merge_ctr_kernel<16,4,32><<<pb,tb,0,stream>>>(pd32,pi16,knn,x2,W3,h0,BN);
  edge_kernel<16,4,32><<<eb,et,0,stream>>>(x2,knn,h0,W3,g3,b3,x3,xxb,N);

  // layer 4: 32 -> 64
  knn_kernel<8><<<kb,kt,0,stream>>>(x3,xxb,pd32,pi16,N);
  merge_ctr_kernel<32,8,64><<<pb,tb,0,stream>>>(pd32,pi16,knn,x3,W4,h0,BN);
  edge_kernel<32,8,64><<<eb,et,0,stream>>>(x3,knn,h0,W4,g4,b4,x4,xxb,N);

  final_max_kernel<<<dim3(4,B),dim3(256),0,stream>>>(x1,x2,x3,x4,out,N);
}

// Round 16
// 899.825 us; speedup vs baseline: 1.5584x; 1.0090x over previous
//
#include <hip/hip_runtime.h>

#define K_NN 20
#define LN_EPS 1e-5f
#define NEG_SLOPE 0.2f
#define BUFSZ 15
#define ARRSZ 32

__device__ __forceinline__ unsigned ordf(float f){
  unsigned u = __float_as_uint(f);
  return u ^ (((unsigned)((int)u >> 31)) | 0x80000000u);
}
__device__ __forceinline__ float unordf(unsigned u){
  unsigned m = ((int)u < 0) ? 0x80000000u : 0xFFFFFFFFu;
  return __uint_as_float(u ^ m);
}

__device__ __forceinline__ void ce_desc(unsigned long long &a, unsigned long long &b){
  unsigned long long mx = a>b ? a : b;
  unsigned long long mn = a>b ? b : a;
  a = mx; b = mn;
}

__device__ __forceinline__ void sort16_desc(unsigned long long (&v)[16]){
  #pragma unroll
  for (int k=2;k<=16;k<<=1){
    #pragma unroll
    for (int j=k>>1;j>0;j>>=1){
      #pragma unroll
      for (int i=0;i<16;++i){
        int l = i ^ j;
        if (l > i){
          if ((i & k) == 0) ce_desc(v[i], v[l]);
          else              ce_desc(v[l], v[i]);
        }
      }
    }
  }
}

// full 32-wide bitonic merge cleanup (valid for any genuine 32-long bitonic
// sequence, e.g. the valley produced by the max-split of two desc lists).
// Round-8 lesson: never prune with virtual -inf pads (not bitonic).
__device__ __forceinline__ void bmerge32_desc(unsigned long long (&v)[32]){
  #pragma unroll
  for (int d=16; d>0; d>>=1){
    #pragma unroll
    for (int i=0;i<32;++i){
      if ((i & d) == 0) ce_desc(v[i], v[i|d]);
    }
  }
}

// ---------------- normalize (+ fused layer-1 xx) ----------------
__global__ __launch_bounds__(1024) void normalize_kernel(const float* __restrict__ x,
                                                         float* __restrict__ xn,
                                                         float* __restrict__ xxo, int N){
  __shared__ float red[1024];
  __shared__ float ms[4];
  const int b = blockIdx.x;
  const int t = threadIdx.x;
  const float* xb = x + (size_t)b*3*N;
  float s0=0.f,s1=0.f,s2=0.f;
  for (int n=t;n<N;n+=1024){ s0+=xb[n]; s1+=xb[N+n]; s2+=xb[2*N+n]; }
  red[t]=s0; __syncthreads();
  for(int o=512;o>0;o>>=1){ if(t<o) red[t]+=red[t+o]; __syncthreads(); }
  if(!t) ms[0]=red[0]/(float)N; __syncthreads();
  red[t]=s1; __syncthreads();
  for(int o=512;o>0;o>>=1){ if(t<o) red[t]+=red[t+o]; __syncthreads(); }
  if(!t) ms[1]=red[0]/(float)N; __syncthreads();
  red[t]=s2; __syncthreads();
  for(int o=512;o>0;o>>=1){ if(t<o) red[t]+=red[t+o]; __syncthreads(); }
  if(!t) ms[2]=red[0]/(float)N; __syncthreads();
  const float m0=ms[0], m1=ms[1], m2=ms[2];
  float mx=0.f;
  for (int n=t;n<N;n+=1024){
    float a=xb[n]-m0, c1=xb[N+n]-m1, c2=xb[2*N+n]-m2;
    mx = fmaxf(mx, a*a+c1*c1+c2*c2);
  }
  red[t]=mx; __syncthreads();
  for(int o=512;o>0;o>>=1){ if(t<o) red[t]=fmaxf(red[t],red[t+o]); __syncthreads(); }
  if(!t) ms[3]=sqrtf(red[0])+1e-8f; __syncthreads();
  const float md=ms[3];
  for (int n=t;n<N;n+=1024){
    float a=xb[n]-m0, c1=xb[N+n]-m1, c2=xb[2*N+n]-m2;
    float4 v; v.x=a/md; v.y=c1/md; v.z=c2/md; v.w=0.f;
    reinterpret_cast<float4*>(xn)[(size_t)b*N+n]=v;
    float s=0.f;
    s=fmaf(v.x,v.x,s); s=fmaf(v.y,v.y,s); s=fmaf(v.z,v.z,s); s=fmaf(v.w,v.w,s);
    xxo[b*N+n]=s;
  }
}

// ---------------- KNN: split-2 candidate space, 8 waves/block ----------------
// Proven round-11 core (s_load candidate path; seed + float-threshold +
// chunked hot loop + LDS-buffered flush). Converged: 8-waves/SIMD is
// infeasible (arr[32] u64 = 64 VGPR alone; (512,8) forces scratch spill —
// the r12/r13 1.25 GB/dispatch failure mode).
template<int CP4>
__global__ __launch_bounds__(512,4) void knn_kernel(const float* __restrict__ feat,
                                                    const float* __restrict__ xx,
                                                    unsigned* __restrict__ pd32,
                                                    unsigned short* __restrict__ pi16,
                                                    int N){
  __shared__ unsigned long long sbuf[BUFSZ*512];   // 61440 B, re-aliased for merge phase
  const int ng = N>>6;
  const int s  = blockIdx.x & 1;
  const int gi = blockIdx.x >> 1;
  const int b  = gi / ng;
  const int n0 = (gi % ng) << 6;
  const int tid = threadIdx.x;
  const int lane = tid & 63;
  const int w = __builtin_amdgcn_readfirstlane(tid >> 6);
  const int bN = b*N;
  const int n = n0 + lane;
  const float4* fb = reinterpret_cast<const float4*>(feat);
  float4 own[CP4];
  #pragma unroll
  for (int i=0;i<CP4;++i) own[i] = fb[(size_t)(bN+n)*CP4 + i];

  auto pdof = [&](int m)->float{
    const float4* cp = fb + (size_t)(bN+m)*CP4;   // wave-uniform -> s_load
    float d0=0.f, d1=0.f;
    #pragma unroll
    for (int i=0;i<CP4;++i){
      float4 c = cp[i];
      d0 = fmaf(own[i].x,c.x,d0);
      d1 = fmaf(own[i].y,c.y,d1);
      d0 = fmaf(own[i].z,c.z,d0);
      d1 = fmaf(own[i].w,c.w,d1);
    }
    return fmaf(2.f, d0+d1, -xx[bN+m]);      // -xxn dropped (row-constant shift)
  };

  const int m0 = s*(N>>1) + w*(N>>4);        // slice = N/16 per wave

  unsigned long long arr[ARRSZ];             // sorted descending at all times
  float thresh;                              // float (shifted) distance of current 20th best
  int cnt = 0;

  // ---- seed: exact sorted top-32 of first 32 candidates (genuine valley-32) ----
  {
    unsigned long long bv1[16], bv2[16];
    #pragma unroll
    for (int j=0;j<16;++j){
      float pd = pdof(m0+j);
      bv1[j] = ((unsigned long long)ordf(pd)<<32) | (unsigned)((m0+j) ^ 0xFFFF);
    }
    sort16_desc(bv1);
    #pragma unroll
    for (int j=0;j<16;++j){
      float pd = pdof(m0+16+j);
      bv2[j] = ((unsigned long long)ordf(pd)<<32) | (unsigned)((m0+16+j) ^ 0xFFFF);
    }
    sort16_desc(bv2);
    #pragma unroll
    for (int i=0;i<ARRSZ;++i) arr[i] = (i<16) ? bv1[i] : bv2[31-i];
    bmerge32_desc(arr);
    thresh = unordf((unsigned)(arr[K_NN-1]>>32));   // exact 20th best so far
  }

  auto do_flush = [&](){
    unsigned long long bv[16];
    #pragma unroll
    for (int q=0;q<16;++q){
      unsigned long long v = (q<BUFSZ) ? sbuf[q*512 + tid] : 0ull;
      bv[q] = (q < cnt) ? v : 0ull;
    }
    sort16_desc(bv);
    #pragma unroll
    for (int i=16;i<32;++i){
      unsigned long long t2 = bv[31-i];
      arr[i] = arr[i] > t2 ? arr[i] : t2;
    }
    bmerge32_desc(arr);                      // valley-32 -> sorted desc (proven)
    thresh = unordf((unsigned)(arr[K_NN-1]>>32));
    cnt = 0;
  };

  // ---- main loop: chunks of C candidates (batched loads -> ILP) ----
  constexpr int C = (CP4==1) ? 8 : 4;
  const int nchunks = ((N>>4) - 32) / C;
  for (int ch=0; ch<nchunks; ++ch){
    const int mc = m0 + 32 + ch*C;
    float pdv[C];
    #pragma unroll
    for (int j=0;j<C;++j) pdv[j] = pdof(mc+j);
    #pragma unroll
    for (int j=0;j<C;++j){
      if (pdv[j] >= thresh){
        sbuf[cnt*512 + tid] =
          ((unsigned long long)ordf(pdv[j])<<32) | (unsigned)((mc+j) ^ 0xFFFF);
        ++cnt;
      }
    }
    if (__ballot(cnt >= BUFSZ-C)) do_flush();   // pre-chunk cnt <= BUFSZ-C-1 -> max fill 14
  }
  if (__ballot(cnt > 0)) do_flush();

  __syncthreads();
  // re-alias LDS for the 8-list block merge.
  // lkh = FULL 32-bit ordered distance (arr>>32); lki = 16-bit idx^0xFFFF.
  unsigned* lkh = (unsigned*)sbuf;                              // 8*20*64*4 = 40960
  unsigned short* lki = (unsigned short*)(((char*)sbuf)+40960); // 8*20*64*2 = 20480
  #pragma unroll
  for (int i=0;i<K_NN;++i){
    lkh[((w*K_NN+i)<<6)+lane] = (unsigned)(arr[i]>>32);
    lki[((w*K_NN+i)<<6)+lane] = (unsigned short)(arr[i]&0xFFFFu);
  }
  __syncthreads();
  if (tid < 64){
    const int l = tid;
    unsigned long long heads[8];
    #pragma unroll
    for (int j=0;j<8;++j){
      int q0=((j*K_NN)<<6)+l;
      heads[j]=((unsigned long long)lkh[q0]<<16)|(unsigned long long)lki[q0];
    }
    unsigned long long pk=0ull;      // 8 x 5-bit counters
    const size_t pbase = ((size_t)(bN+n0+l)*2 + s)*K_NN;
    for (int kk=0;kk<K_NN;++kk){
      unsigned long long best=heads[0]; int bj=0;
      #pragma unroll
      for (int j=1;j<8;++j){ bool gg=heads[j]>best; best=gg?heads[j]:best; bj=gg?j:bj; }
      pd32[pbase+kk] = (unsigned)(best>>16);          // full ordered distance
      pi16[pbase+kk] = (unsigned short)(best & 0xFFFFu);
      unsigned pos = (unsigned)((pk>>(bj*5))&0x1Ful)+1u;
      pk += (1ull<<(bj*5));
      unsigned long long nv = 0ull;
      if (pos<K_NN){
        int q1=((bj*K_NN+(int)pos)<<6)+l;
        nv=((unsigned long long)lkh[q1]<<16)|(unsigned long long)lki[q1];
      }
      #pragma unroll
      for (int j=0;j<8;++j) heads[j]=(j==bj)?nv:heads[j];
    }
  }
}

// ---------------- fused: merge the two half top-20 lists + ctr half matmul ----------------
template<int CIN,int CP4,int O>
__global__ __launch_bounds__(256) void merge_ctr_kernel(const unsigned* __restrict__ pd32,
                                                        const unsigned short* __restrict__ pi16,
                                                        int* __restrict__ idx_out,
                                                        const float* __restrict__ feat,
                                                        const float* __restrict__ W,
                                                        float* __restrict__ h0, int total){
  int i = blockIdx.x*256 + threadIdx.x;
  if (i>=total) return;
  // ---- 2-way merge of sorted half-lists ----
  {
    const unsigned* d0 = pd32 + (size_t)i*2*K_NN;
    const unsigned short* i0 = pi16 + (size_t)i*2*K_NN;
    const unsigned* d1 = d0 + K_NN;
    const unsigned short* i1 = i0 + K_NN;
    int a=0, c=0;
    int* op = idx_out + (size_t)i*K_NN;
    #pragma unroll 4
    for (int k=0;k<K_NN;++k){
      unsigned long long k0 = ((unsigned long long)d0[a]<<16) | i0[a];
      unsigned long long k1 = ((unsigned long long)d1[c]<<16) | i1[c];
      bool t = k0 > k1;
      unsigned long long best = t ? k0 : k1;
      op[k] = (int)(((unsigned)best & 0xFFFFu) ^ 0xFFFFu);
      a += t; c += !t;
    }
  }
  // ---- ctr half of the edge matmul ----
  {
    const float4* p = reinterpret_cast<const float4*>(feat)+(size_t)i*CP4;
    float c[CP4*4];
    #pragma unroll
    for (int j=0;j<CP4;++j){
      float4 v=p[j];
      c[4*j+0]=v.x; c[4*j+1]=v.y; c[4*j+2]=v.z; c[4*j+3]=v.w;
    }
    float* hp = h0 + (size_t)i*O;
    #pragma unroll
    for (int o=0;o<O;++o){
      const float* wr = W + o*(2*CIN) + CIN;   // uniform -> s_load
      float a=0.f;
      #pragma unroll
      for (int cc=0;cc<CIN;++cc) a=fmaf(wr[cc],c[cc],a);
      hp[o]=a;
    }
  }
}

// ---------------- edge conv: thread per (point, neighbor); fused next-layer xx ----------------
// K-max via 8-slot-spread LDS atomicMax (k&7): slot populations {3,3,3,3,2,2,2,2}
// -> max 3-way same-address contention (was 5-way with 4 slots, 20-way with 1).
// Max of slot-maxes == global max (exact). LDS worst case (O=64) = 32 KB.
template<int CIN,int CP4,int O>
__global__ __launch_bounds__(320) void edge_kernel(const float* __restrict__ feat,
      const int* __restrict__ knn_idx, const float* __restrict__ h0,
      const float* __restrict__ W, const float* __restrict__ g, const float* __restrict__ bb,
      float* __restrict__ outf, float* __restrict__ xxo, int N){
  __shared__ unsigned ob[16*O*8];
  const int t = threadIdx.x;
  const int p = t/K_NN, k = t - p*K_NN;
  const int b = blockIdx.y;
  const int n = blockIdx.x*16 + p;
  const int bN = b*N;
  for (int v=t; v<16*O*8; v+=320) ob[v]=0u;
  __syncthreads();
  const int m = knn_idx[(size_t)(bN+n)*K_NN + k];
  const float4* fb = reinterpret_cast<const float4*>(feat);
  float d[CP4*4];
  #pragma unroll
  for (int j=0;j<CP4;++j){
    float4 a = fb[(size_t)(bN+m)*CP4+j];
    float4 c = fb[(size_t)(bN+n)*CP4+j];
    d[4*j+0]=a.x-c.x; d[4*j+1]=a.y-c.y; d[4*j+2]=a.z-c.z; d[4*j+3]=a.w-c.w;
  }
  float h[O];
  const float4* hp = reinterpret_cast<const float4*>(h0 + (size_t)(bN+n)*O);
  #pragma unroll
  for (int j=0;j<O/4;++j){ float4 v=hp[j]; h[4*j]=v.x; h[4*j+1]=v.y; h[4*j+2]=v.z; h[4*j+3]=v.w; }
  #pragma unroll
  for (int o=0;o<O;++o){
    const float* wr = W + o*(2*CIN);          // uniform -> s_load
    float a=h[o];
    #pragma unroll
    for (int cc=0;cc<CIN;++cc) a=fmaf(wr[cc],d[cc],a);
    h[o]=a;
  }
  float mean=0.f;
  #pragma unroll
  for (int o=0;o<O;++o) mean+=h[o];
  mean *= (1.f/(float)O);
  float var=0.f;
  #pragma unroll
  for (int o=0;o<O;++o){ float dd=h[o]-mean; var=fmaf(dd,dd,var); }
  var *= (1.f/(float)O);
  const float r = rsqrtf(var+LN_EPS);
  const int slot = k & 7;
  #pragma unroll
  for (int o=0;o<O;++o){
    float hv = (h[o]-mean)*r*g[o]+bb[o];
    hv = (hv>=0.f)? hv : NEG_SLOPE*hv;
    atomicMax(&ob[((p*O+o)<<3) + slot], ordf(hv));
  }
  __syncthreads();
  for (int v=t; v<16*O; v+=320){
    int pp=v/O, oo=v-pp*O;
    unsigned u0=ob[v*8+0], u1=ob[v*8+1], u2=ob[v*8+2], u3=ob[v*8+3];
    unsigned u4=ob[v*8+4], u5=ob[v*8+5], u6=ob[v*8+6], u7=ob[v*8+7];
    unsigned a0=u0>u1?u0:u1, a1=u2>u3?u2:u3, a2=u4>u5?u4:u5, a3=u6>u7?u6:u7;
    a0=a0>a1?a0:a1; a2=a2>a3?a2:a3;
    unsigned mm=a0>a2?a0:a2;
    outf[(size_t)(bN+blockIdx.x*16+pp)*O+oo]=unordf(mm);
  }
  // fused xx for the next layer (bitwise-identical fmaf chain)
  if (t < 16){
    float s=0.f;
    for (int oo=0;oo<O;++oo){
      int base=(t*O+oo)*8;
      unsigned u0=ob[base+0], u1=ob[base+1], u2=ob[base+2], u3=ob[base+3];
      unsigned u4=ob[base+4], u5=ob[base+5], u6=ob[base+6], u7=ob[base+7];
      unsigned a0=u0>u1?u0:u1, a1=u2>u3?u2:u3, a2=u4>u5?u4:u5, a3=u6>u7?u6:u7;
      a0=a0>a1?a0:a1; a2=a2>a3?a2:a3;
      unsigned mm=a0>a2?a0:a2;
      float f = unordf(mm);
      s = fmaf(f,f,s);
    }
    xxo[bN + blockIdx.x*16 + t] = s;
  }
}

// ---------------- global max pool over points ----------------
__global__ __launch_bounds__(256) void final_max_kernel(const float* __restrict__ x1,
    const float* __restrict__ x2, const float* __restrict__ x3, const float* __restrict__ x4,
    float* __restrict__ out, int N){
  __shared__ float red[256];
  const int L=blockIdx.x, b=blockIdx.y;
  const float* f; int O, off;
  if (L==0){f=x1;O=16;off=0;}
  else if (L==1){f=x2;O=16;off=16;}
  else if (L==2){f=x3;O=32;off=32;}
  else {f=x4;O=64;off=64;}
  const int t=threadIdx.x;
  const int c=t%O, s=t/O, S=256/O;
  float acc=-3.402823466e38f;
  for (int n=s;n<N;n+=S) acc=fmaxf(acc, f[(size_t)(b*N+n)*O+c]);
  red[t]=acc; __syncthreads();
  if (t<O){
    float a=red[t];
    for (int ss=1;ss<S;++ss) a=fmaxf(a,red[ss*O+t]);
    out[b*128+off+t]=a;
  }
}

extern "C" void kernel_launch(void* const* d_in, const int* in_sizes, int n_in,
                              void* d_out, int out_size, void* d_ws, size_t ws_size,
                              hipStream_t stream){
  const float* x  = (const float*)d_in[0];
  const float* W1 = (const float*)d_in[1];  const float* g1=(const float*)d_in[2];  const float* b1=(const float*)d_in[3];
  const float* W2 = (const float*)d_in[4];  const float* g2=(const float*)d_in[5];  const float* b2=(const float*)d_in[6];
  const float* W3 = (const float*)d_in[7];  const float* g3=(const float*)d_in[8];  const float* b3=(const float*)d_in[9];
  const float* W4 = (const float*)d_in[10]; const float* g4=(const float*)d_in[11]; const float* b4=(const float*)d_in[12];
  float* out=(float*)d_out;
  const int B=4;
  const int N=in_sizes[0]/(3*B);
  const int BN=B*N;

  char* ws=(char*)d_ws;
  size_t off=0;
  auto alloc=[&](size_t bytes)->void*{ void* p=ws+off; off=(off+bytes+255)&~(size_t)255; return p; };
  float* xn =(float*)alloc((size_t)BN*4*4);
  float* x1 =(float*)alloc((size_t)BN*16*4);
  float* x2 =(float*)alloc((size_t)BN*16*4);
  float* x3 =(float*)alloc((size_t)BN*32*4);
  float* x4 =(float*)alloc((size_t)BN*64*4);
  float* xxb=(float*)alloc((size_t)BN*4);
  int*   knn=(int*)  alloc((size_t)BN*K_NN*4);
  float* h0 =(float*)alloc((size_t)BN*64*4);
  unsigned*       pd32=(unsigned*)      alloc((size_t)BN*2*K_NN*4);  // own buffer (no h0 alias:
  unsigned short* pi16=(unsigned short*)alloc((size_t)BN*2*K_NN*2);  // merge_ctr writes h0 concurrently)

  dim3 pb((BN+255)/256), tb(256);
  dim3 kb(B*(N/64)*2), kt(512);
  dim3 eb(N/16,B), et(320);

  normalize_kernel<<<dim3(B),dim3(1024),0,stream>>>(x,xn,xxb,N);

  // layer 1: 3 -> 16
  knn_kernel<1><<<kb,kt,0,stream>>>(xn,xxb,pd32,pi16,N);
  merge_ctr_kernel<3,1,16><<<pb,tb,0,stream>>>(pd32,pi16,knn,xn,W1,h0,BN);
  edge_kernel<3,1,16><<<eb,et,0,stream>>>(xn,knn,h0,W1,g1,b1,x1,xxb,N);

  // layer 2: 16 -> 16
  knn_kernel<4><<<kb,kt,0,stream>>>(x1,xxb,pd32,pi16,N);
  merge_ctr_kernel<16,4,16><<<pb,tb,0,stream>>>(pd32,pi16,knn,x1,W2,h0,BN);
  edge_kernel<16,4,16><<<eb,et,0,stream>>>(x1,knn,h0,W2,g2,b2,x2,xxb,N);

  // layer 3: 16 -> 32
  knn_kernel<4><<<kb,kt,0,stream>>>(x2,xxb,pd32,pi16,N);
  merge_ctr_kernel<16,4,32><<<pb,tb,0,stream>>>(pd32,pi16,knn,x2,W3,h0,BN);
  edge_kernel<16,4,32><<<eb,et,0,stream>>>(x2,knn,h0,W3,g3,b3,x3,xxb,N);

  // layer 4: 32 -> 64
  knn_kernel<8><<<kb,kt,0,stream>>>(x3,xxb,pd32,pi16,N);
  merge_ctr_kernel<32,8,64><<<pb,tb,0,stream>>>(pd32,pi16,knn,x3,W4,h0,BN);
  edge_kernel<32,8,64><<<eb,et,0,stream>>>(x3,knn,h0,W4,g4,b4,x4,xxb,N);

  final_max_kernel<<<dim3(4,B),dim3(256),0,stream>>>(x1,x2,x3,x4,out,N);
}